// Round 7
// baseline (2078.200 us; speedup 1.0000x reference)
//
#include <hip/hip_runtime.h>
#include <math.h>

#define B_   512
#define T_   800
#define FIN  3
#define NF   128
#define KW   15
#define HID  150
#define LOUT 393
#define G4   600
#define NPAD 640
#define EPS  1e-5f

#define NT_  38          // whh N tiles of 16 over 608
#define KT_  5           // whh K tiles of 32 over 160
#define HSTR 152
#define PNT  40          // wih N tiles of 16 over 640
#define PKT  4           // wih K tiles of 32 over 128

typedef _Float16 half8 __attribute__((ext_vector_type(8)));
typedef float f32x4 __attribute__((ext_vector_type(4)));

__device__ __forceinline__ float hsig(float x){ return fminf(fmaxf(0.2f*x+0.5f,0.f),1.f); }
__device__ __forceinline__ float ftanh(float x){ float e=__expf(2.f*x); return 1.f - 2.f/(e+1.f); }

// ------- conv + relu + maxpool2 + f16 store + AdaBN1 stats (fused) -------
__global__ __launch_bounds__(512) void k_conv2(const float* __restrict__ x,
        const float* __restrict__ cw, const float* __restrict__ cb,
        _Float16* __restrict__ y16, float* __restrict__ st){
  __shared__ float xs[FIN][800];
  __shared__ float wl[NF*FIN*KW];      // 5760
  __shared__ float rs[4][128], rq[4][128];
  int tid = threadIdx.x;
  int b = blockIdx.x;
  for (int i=tid;i<FIN*800;i+=512) (&xs[0][0])[i] = x[(size_t)b*(FIN*T_) + i];
  for (int i=tid;i<NF*FIN*KW;i+=512) wl[i]=cw[i];
  __syncthreads();
  int c = tid & 127, li = tid >> 7;
  float wr[FIN*KW];
  #pragma unroll
  for (int i=0;i<FIN*KW;i++) wr[i]=wl[c*FIN*KW+i];
  float cbv = cb[c];
  float s=0.f, q=0.f;
  for (int l=li; l<LOUT; l+=4){
    float a0=0.f, a1=0.f;
    #pragma unroll
    for (int f=0;f<FIN;f++){
      const float2* xp = (const float2*)&xs[f][0] + l;
      float xv[16];
      #pragma unroll
      for (int p=0;p<8;p++){ float2 v=xp[p]; xv[2*p]=v.x; xv[2*p+1]=v.y; }
      #pragma unroll
      for (int k=0;k<KW;k++){ float w=wr[f*KW+k]; a0 += w*xv[k]; a1 += w*xv[k+1]; }
    }
    float v = fmaxf(fmaxf(a0,a1)+cbv, 0.f);
    y16[((size_t)b*LOUT + l)*NF + c] = (_Float16)v;
    s += v; q += v*v;
  }
  rs[li][c]=s; rq[li][c]=q;
  __syncthreads();
  if (tid < 128){
    float ts = rs[0][c]+rs[1][c]+rs[2][c]+rs[3][c];
    float tq = rq[0][c]+rq[1][c]+rq[2][c]+rq[3][c];
    atomicAdd(&st[c], ts);
    atomicAdd(&st[128+c], tq);
  }
}

// -------- bias fold: be[g] = b_ih+b_hh + sum_f d[f]*w_ih[g][f] --------
__global__ void k_prep_bias(const float* __restrict__ st,
    const float* __restrict__ g1, const float* __restrict__ b1v,
    const float* __restrict__ wf, const float* __restrict__ wb,
    const float* __restrict__ bif, const float* __restrict__ bhf,
    const float* __restrict__ bib, const float* __restrict__ bhb,
    float* __restrict__ bef, float* __restrict__ beb){
  int id = blockIdx.x*256 + threadIdx.x;
  if (id >= 2*NPAD) return;
  int dir = id/NPAD, g = id%NPAD;
  float* be = dir? beb : bef;
  if (g >= G4){ be[g]=0.f; return; }
  const float* wih = dir? wb : wf;
  float bias = dir? (bib[g]+bhb[g]) : (bif[g]+bhf[g]);
  const float Ninv = 1.f/((float)B_*(float)LOUT);
  for (int f=0;f<NF;f++){
    float m = st[f]*Ninv;
    float var = st[NF+f]*Ninv - m*m;
    float a = g1[f]*rsqrtf(var+EPS);
    float d = b1v[f] - m*a;
    bias += d*wih[g*NF+f];
  }
  be[g] = bias;
}

// -------- pack AdaBN-folded w_ih into f16 MFMA B-fragments --------
__global__ void k_prep_wih(const float* __restrict__ st,
    const float* __restrict__ g1,
    const float* __restrict__ wf, const float* __restrict__ wb,
    _Float16* __restrict__ wT16){
  int id = blockIdx.x*256 + threadIdx.x;
  if (id >= 2*PNT*PKT*64) return;
  int lane = id & 63;
  int kt = (id>>6) & 3;
  int nt = (id>>8) % PNT;
  int dir = id / (PNT*PKT*64);
  const float* wih = dir? wb : wf;
  int n = nt*16 + (lane&15);
  int kb = kt*32 + (lane>>4)*8;
  const float Ninv = 1.f/((float)B_*(float)LOUT);
  half8 v;
  #pragma unroll
  for (int j=0;j<8;j++){
    int k = kb+j;
    float m = st[k]*Ninv;
    float var = st[NF+k]*Ninv - m*m;
    float a = g1[k]*rsqrtf(var+EPS);
    float f = (n < G4) ? wih[(size_t)n*NF + k]*a : 0.f;
    v[j] = (_Float16)f;
  }
  *(half8*)&wT16[(size_t)id*8] = v;
}

// -------- pack w_hh into f16 MFMA B-fragments --------
__global__ void k_prep_whh(const float* __restrict__ whf, const float* __restrict__ whb,
                           _Float16* __restrict__ wfrag){
  int id = blockIdx.x*256 + threadIdx.x;
  if (id >= 2*NT_*KT_*64) return;
  int lane = id & 63;
  int rest = id >> 6;
  int kt = rest % KT_;
  int nt = (rest/KT_) % NT_;
  int dir = rest / (KT_*NT_);
  const float* wh = dir? whb : whf;
  int n = nt*16 + (lane&15);
  int kb = kt*32 + (lane>>4)*8;
  half8 v;
  #pragma unroll
  for (int j=0;j<8;j++){
    int k = kb + j;
    float f = (n < G4 && k < HID) ? wh[(size_t)n*HID + k] : 0.f;
    v[j] = (_Float16)f;
  }
  *(half8*)&wfrag[(size_t)id*8] = v;
}

// ---------------- projection via f16 MFMA (unchanged) ----------------
__global__ __launch_bounds__(256) void k_proj2(const _Float16* __restrict__ y16,
    const _Float16* __restrict__ wT16,
    const float* __restrict__ bef, const float* __restrict__ beb,
    _Float16* __restrict__ pre16f, _Float16* __restrict__ pre16b,
    int t0f, int tc){
  __shared__ _Float16 Ds[128*136];
  __shared__ float bs[128];
  int dir = blockIdx.z;
  const _Float16* wfp = wT16 + (size_t)dir*PNT*PKT*64*8;
  const float* be = dir? beb : bef;
  _Float16* pre = dir? pre16b : pre16f;
  int tid = threadIdx.x, lane = tid&63, w = tid>>6;
  int trel = blockIdx.x>>2, bb = (blockIdx.x&3)*128;
  int t = dir ? (LOUT-1-t0f-trel) : (t0f+trel);
  int n0 = blockIdx.y*128;
  if (tid < 32) *(float4*)&bs[tid*4] = *(const float4*)&be[n0 + tid*4];

  f32x4 acc[2][8];
  #pragma unroll
  for (int i=0;i<2;i++)
    #pragma unroll
    for (int j=0;j<8;j++) acc[i][j] = (f32x4){0,0,0,0};

  int arow = lane&15, aq = (lane>>4)*8;
  const _Float16* a0p = y16 + ((size_t)(bb + (2*w)*16 + arow)*LOUT + t)*NF + aq;
  const _Float16* a1p = a0p + (size_t)16*LOUT*NF;
  int nb = n0 >> 4;
  #pragma unroll
  for (int kt=0; kt<PKT; kt++){
    half8 a0 = *(const half8*)(a0p + kt*32);
    half8 a1 = *(const half8*)(a1p + kt*32);
    #pragma unroll
    for (int nt=0; nt<8; nt++){
      half8 bf = *(const half8*)&wfp[(size_t)(((nb+nt)*PKT + kt)*64 + lane)*8];
      acc[0][nt] = __builtin_amdgcn_mfma_f32_16x16x32_f16(a0, bf, acc[0][nt], 0,0,0);
      acc[1][nt] = __builtin_amdgcn_mfma_f32_16x16x32_f16(a1, bf, acc[1][nt], 0,0,0);
    }
  }
  __syncthreads();
  int dcol = lane&15, dq = (lane>>4)*4;
  #pragma unroll
  for (int mi=0; mi<2; mi++){
    int rowb = (2*w+mi)*16 + dq;
    #pragma unroll
    for (int nt=0; nt<8; nt++){
      int colL = nt*16 + dcol;
      float bv = bs[colL];
      #pragma unroll
      for (int r=0;r<4;r++)
        Ds[(rowb+r)*136 + colL] = (_Float16)(acc[mi][nt][r] + bv);
    }
  }
  __syncthreads();
  int row = tid>>1, h = tid&1;
  const _Float16* src = &Ds[row*136 + h*64];
  _Float16* dst = pre + ((size_t)(trel*B_ + bb + row))*NPAD + n0 + h*64;
  #pragma unroll
  for (int qq=0; qq<8; qq++)
    *(float4*)(dst + qq*8) = *(const float4*)(src + qq*8);
}

// ---------------- recurrence v3: M=4/block, 256 blocks, 768 thr ----------------
// wave w owns n-tiles [4w, 4w+4) of 38; 20 frags = 80 VGPR. Cell: 1 unit/thread.
__global__ __launch_bounds__(768)
void k_rec3(const _Float16* __restrict__ wfrag,
            const _Float16* __restrict__ pref, const _Float16* __restrict__ preb,
            float* __restrict__ hst, float* __restrict__ cst, float* __restrict__ mst,
            float* __restrict__ pooled, int tc, int first, int last){
  int dir = blockIdx.x >> 7;
  int b0 = (blockIdx.x & 127) * 4;
  const _Float16* pre = dir? preb : pref;
  int tid = threadIdx.x, lane = tid & 63, w = tid >> 6;

  __shared__ __align__(16) _Float16 hh[16][168];   // rows 0-3 live, 4-15 zero
  __shared__ float dls[4][612];

  int ntbase = w*4;
  int cnt = 38 - ntbase; if (cnt < 0) cnt = 0; if (cnt > 4) cnt = 4;
  const _Float16* wf = wfrag + (size_t)dir*NT_*KT_*64*8;
  half8 bfr[4][5];
  #pragma unroll
  for (int i=0;i<4;i++){
    int ntc = (i<cnt)? (ntbase+i) : 0;
    #pragma unroll
    for (int kt=0;kt<KT_;kt++)
      bfr[i][kt] = *(const half8*)&wf[(size_t)((ntc*KT_+kt)*64 + lane)*8];
  }

  int b = tid/150, u = tid - b*150;
  bool cellv = tid < 600;

  for (int i=tid; i<16*168; i+=768) (&hh[0][0])[i] = (_Float16)0.f;
  __syncthreads();
  float c=0.f, m=-1e30f, hl=0.f;
  if (!first && cellv){
    size_t gi = ((size_t)(dir*B_ + b0 + b))*HSTR + u;
    c = cst[gi]; m = mst[gi]; hl = hst[gi];
    hh[b][u] = (_Float16)hl;
  }
  float pf4[4] = {0,0,0,0};
  if (cellv){
    const _Float16* pr = pre + ((size_t)(b0 + b))*NPAD + u;
    #pragma unroll
    for (int g=0; g<4; g++) pf4[g] = (float)pr[g*HID];
  }
  __syncthreads();

  int arow = lane & 15, koff = (lane>>4)*8;
  bool dw = (lane < 16);

  for (int t=0; t<tc; t++){
    // prefetch t+1 (consumed next iteration)
    float pn4[4] = {0,0,0,0};
    if (t+1 < tc && cellv){
      const _Float16* pr = pre + ((size_t)(t+1)*B_ + b0 + b)*NPAD + u;
      #pragma unroll
      for (int g=0; g<4; g++) pn4[g] = (float)pr[g*HID];
    }
    // MFMA phase
    f32x4 acc[4];
    #pragma unroll
    for (int i=0;i<4;i++) acc[i] = (f32x4){0,0,0,0};
    #pragma unroll
    for (int kt=0; kt<KT_; kt++){
      half8 a = *(const half8*)&hh[arow][kt*32 + koff];
      #pragma unroll
      for (int i=0;i<4;i++)
        if (i < cnt)
          acc[i] = __builtin_amdgcn_mfma_f32_16x16x32_f16(a, bfr[i][kt], acc[i], 0,0,0);
    }
    if (dw){
      #pragma unroll
      for (int i=0;i<4;i++){
        if (i < cnt){
          int col = (ntbase+i)*16 + lane;
          #pragma unroll
          for (int r=0;r<4;r++) dls[r][col] = acc[i][r];
        }
      }
    }
    __syncthreads();
    // cell phase: 1 unit per thread
    if (cellv){
      float pi = dls[b][u]      + pf4[0];
      float pfg= dls[b][u+150]  + pf4[1];
      float pg = dls[b][u+300]  + pf4[2];
      float po = dls[b][u+450]  + pf4[3];
      float ig=hsig(pi), fg=hsig(pfg), og=hsig(po), gg=ftanh(pg);
      c = fg*c + ig*gg;
      float hv = og*ftanh(c);
      m = fmaxf(m, hv);
      hl = hv;
      hh[b][u] = (_Float16)hv;
    }
    #pragma unroll
    for (int g=0;g<4;g++) pf4[g] = pn4[g];
    __syncthreads();
  }

  if (cellv){
    size_t gi = ((size_t)(dir*B_ + b0 + b))*HSTR + u;
    cst[gi]=c; mst[gi]=m; hst[gi]=hl;
    if (last) pooled[(size_t)(b0+b)*300 + dir*HID + u] = m;
  }
}

// ---------------- tails ----------------
__global__ void k_stats2(const float* __restrict__ pooled,
    const float* __restrict__ g2, const float* __restrict__ b2,
    float* __restrict__ a2, float* __restrict__ d2){
  int f = threadIdx.x;
  if (f >= 300) return;
  float s=0.f,q=0.f;
  for (int b=0;b<B_;b++){ float v = pooled[(size_t)b*300+f]; s+=v; q+=v*v; }
  float m = s*(1.f/B_), var = q*(1.f/B_) - m*m;
  float a = g2[f]*rsqrtf(var+EPS);
  a2[f]=a; d2[f]=b2[f]-m*a;
}

__global__ void k_fc1(const float* __restrict__ pooled,
    const float* __restrict__ a2, const float* __restrict__ d2,
    const float* __restrict__ w1, const float* __restrict__ fb1,
    float* __restrict__ z1){
  int o = blockIdx.x*256 + threadIdx.x;
  if (o >= B_*50) return;
  int b = o/50, j = o%50;
  float acc = fb1[j];
  for (int f=0;f<300;f++)
    acc += (a2[f]*pooled[(size_t)b*300+f] + d2[f]) * w1[j*300+f];
  z1[o] = fmaxf(acc,0.f);
}

__global__ void k_stats3(const float* __restrict__ z1,
    const float* __restrict__ g3, const float* __restrict__ b3,
    float* __restrict__ a3, float* __restrict__ d3){
  int f = threadIdx.x;
  if (f >= 50) return;
  float s=0.f,q=0.f;
  for (int b=0;b<B_;b++){ float v = z1[(size_t)b*50+f]; s+=v; q+=v*v; }
  float m = s*(1.f/B_), var = q*(1.f/B_) - m*m;
  float a = g3[f]*rsqrtf(var+EPS);
  a3[f]=a; d3[f]=b3[f]-m*a;
}

__global__ void k_fc2(const float* __restrict__ z1,
    const float* __restrict__ a3, const float* __restrict__ d3,
    const float* __restrict__ w2, const float* __restrict__ fb2,
    float* __restrict__ out){
  int b = blockIdx.x;
  int t = threadIdx.x;
  __shared__ float zl[50];
  __shared__ float lg[10];
  if (t<50) zl[t] = a3[t]*z1[(size_t)b*50+t] + d3[t];
  __syncthreads();
  if (t<10){
    float acc = fb2[t];
    for (int j=0;j<50;j++) acc += zl[j]*w2[t*50+j];
    lg[t]=acc;
  }
  __syncthreads();
  if (t<10){
    float m = lg[0];
    #pragma unroll
    for (int i=1;i<10;i++) m = fmaxf(m,lg[i]);
    float s = 0.f;
    #pragma unroll
    for (int i=0;i<10;i++) s += expf(lg[i]-m);
    out[(size_t)b*10+t] = expf(lg[t]-m)/s;
  }
}

extern "C" void kernel_launch(void* const* d_in, const int* in_sizes, int n_in,
                              void* d_out, int out_size, void* d_ws, size_t ws_size,
                              hipStream_t stream) {
  const float* x    = (const float*)d_in[0];
  const float* cw   = (const float*)d_in[1];
  const float* cb   = (const float*)d_in[2];
  const float* g1   = (const float*)d_in[3];
  const float* b1v  = (const float*)d_in[4];
  const float* wihf = (const float*)d_in[5];
  const float* whhf = (const float*)d_in[6];
  const float* bihf = (const float*)d_in[7];
  const float* bhhf = (const float*)d_in[8];
  const float* wihb = (const float*)d_in[9];
  const float* whhb = (const float*)d_in[10];
  const float* bihb = (const float*)d_in[11];
  const float* bhhb = (const float*)d_in[12];
  const float* g2   = (const float*)d_in[13];
  const float* b2   = (const float*)d_in[14];
  const float* w1   = (const float*)d_in[15];
  const float* fb1  = (const float*)d_in[16];
  const float* g3   = (const float*)d_in[17];
  const float* b3   = (const float*)d_in[18];
  const float* w2   = (const float*)d_in[19];
  const float* fb2  = (const float*)d_in[20];
  float* out = (float*)d_out;

  uint8_t* base = (uint8_t*)d_ws;
  size_t off = 0;
  auto allocB = [&](size_t nbytes)->uint8_t*{
    uint8_t* p = base + off;
    off = (off + nbytes + 255) & ~(size_t)255;
    return p;
  };
  _Float16* y16   = (_Float16*)allocB((size_t)B_*LOUT*NF*2);
  float* st       = (float*)allocB(256*4);
  _Float16* wT16  = (_Float16*)allocB((size_t)2*PNT*PKT*64*8*2);
  float* bef      = (float*)allocB(NPAD*4);
  float* beb      = (float*)allocB(NPAD*4);
  _Float16* wfrag = (_Float16*)allocB((size_t)2*NT_*KT_*64*8*2);
  float* hst      = (float*)allocB((size_t)2*B_*HSTR*4);
  float* cst      = (float*)allocB((size_t)2*B_*HSTR*4);
  float* mst      = (float*)allocB((size_t)2*B_*HSTR*4);
  float* pooled   = (float*)allocB((size_t)B_*300*4);
  float* a2       = (float*)allocB(320*4);
  float* d2       = (float*)allocB(320*4);
  float* z1       = (float*)allocB((size_t)B_*50*4);
  float* a3       = (float*)allocB(64*4);
  float* d3       = (float*)allocB(64*4);
  size_t fixedEnd = off;

  size_t per_t = (size_t)2*B_*NPAD*2;   // both dirs, f16
  size_t avail = (ws_size > fixedEnd + 4096) ? (ws_size - fixedEnd - 4096) : 0;
  int tcmax = (int)(avail / per_t);
  if (tcmax < 1) tcmax = 1;
  if (tcmax > LOUT) tcmax = LOUT;
  int nch = (LOUT + tcmax - 1) / tcmax;
  int TC = (LOUT + nch - 1) / nch;
  _Float16* pre16f = (_Float16*)allocB((size_t)TC*B_*NPAD*2);
  _Float16* pre16b = (_Float16*)allocB((size_t)TC*B_*NPAD*2);

  hipMemsetAsync(st, 0, 256*4, stream);
  k_conv2<<<B_, 512, 0, stream>>>(x, cw, cb, y16, st);
  k_prep_bias<<<(2*NPAD+255)/256, 256, 0, stream>>>(st, g1, b1v, wihf, wihb,
                                                    bihf, bhhf, bihb, bhhb, bef, beb);
  k_prep_wih<<<(2*PNT*PKT*64+255)/256, 256, 0, stream>>>(st, g1, wihf, wihb, wT16);
  k_prep_whh<<<(2*NT_*KT_*64+255)/256, 256, 0, stream>>>(whhf, whhb, wfrag);

  int t0 = 0; int first = 1;
  while (t0 < LOUT){
    int tc = (TC < LOUT - t0) ? TC : (LOUT - t0);
    int lastc = (t0 + tc >= LOUT) ? 1 : 0;
    k_proj2<<<dim3(tc*4, 5, 2), 256, 0, stream>>>(y16, wT16, bef, beb,
                                                  pre16f, pre16b, t0, tc);
    k_rec3<<<256, 768, 0, stream>>>(wfrag, pre16f, pre16b,
                                    hst, cst, mst, pooled, tc, first, lastc);
    t0 += tc; first = 0;
  }
  k_stats2<<<1, 320, 0, stream>>>(pooled, g2, b2, a2, d2);
  k_fc1<<<(B_*50+255)/256, 256, 0, stream>>>(pooled, a2, d2, w1, fb1, z1);
  k_stats3<<<1, 64, 0, stream>>>(z1, g3, b3, a3, d3);
  k_fc2<<<B_, 64, 0, stream>>>(z1, a3, d3, w2, fb2, out);
}

// Round 9
// 1177.956 us; speedup vs baseline: 1.7642x; 1.7642x over previous
//
#include <hip/hip_runtime.h>
#include <math.h>

#define B_   512
#define T_   800
#define FIN  3
#define NF   128
#define KW   15
#define HID  150
#define LOUT 393
#define G4   600
#define NPAD 640
#define EPS  1e-5f

#define NT_  38          // whh N tiles of 16 over 608
#define KT_  5           // whh K tiles of 32 over 160
#define HSTR 152
#define PNT  40          // wih N tiles of 16 over 640
#define PKT  4           // wih K tiles of 32 over 128

typedef _Float16 half8 __attribute__((ext_vector_type(8)));
typedef float f32x4 __attribute__((ext_vector_type(4)));

__device__ __forceinline__ float hsig(float x){ return fminf(fmaxf(0.2f*x+0.5f,0.f),1.f); }
__device__ __forceinline__ float ftanh(float x){ float e=__expf(2.f*x); return 1.f - 2.f/(e+1.f); }

// ------- conv + relu + maxpool2 + f16 store + AdaBN1 stats (fused) -------
__global__ __launch_bounds__(512) void k_conv2(const float* __restrict__ x,
        const float* __restrict__ cw, const float* __restrict__ cb,
        _Float16* __restrict__ y16, float* __restrict__ st){
  __shared__ float xs[FIN][800];
  __shared__ float wl[NF*FIN*KW];      // 5760
  __shared__ float rs[4][128], rq[4][128];
  int tid = threadIdx.x;
  int b = blockIdx.x;
  for (int i=tid;i<FIN*800;i+=512) (&xs[0][0])[i] = x[(size_t)b*(FIN*T_) + i];
  for (int i=tid;i<NF*FIN*KW;i+=512) wl[i]=cw[i];
  __syncthreads();
  int c = tid & 127, li = tid >> 7;
  float wr[FIN*KW];
  #pragma unroll
  for (int i=0;i<FIN*KW;i++) wr[i]=wl[c*FIN*KW+i];
  float cbv = cb[c];
  float s=0.f, q=0.f;
  for (int l=li; l<LOUT; l+=4){
    float a0=0.f, a1=0.f;
    #pragma unroll
    for (int f=0;f<FIN;f++){
      const float2* xp = (const float2*)&xs[f][0] + l;
      float xv[16];
      #pragma unroll
      for (int p=0;p<8;p++){ float2 v=xp[p]; xv[2*p]=v.x; xv[2*p+1]=v.y; }
      #pragma unroll
      for (int k=0;k<KW;k++){ float w=wr[f*KW+k]; a0 += w*xv[k]; a1 += w*xv[k+1]; }
    }
    float v = fmaxf(fmaxf(a0,a1)+cbv, 0.f);
    y16[((size_t)b*LOUT + l)*NF + c] = (_Float16)v;
    s += v; q += v*v;
  }
  rs[li][c]=s; rq[li][c]=q;
  __syncthreads();
  if (tid < 128){
    float ts = rs[0][c]+rs[1][c]+rs[2][c]+rs[3][c];
    float tq = rq[0][c]+rq[1][c]+rq[2][c]+rq[3][c];
    atomicAdd(&st[c], ts);
    atomicAdd(&st[128+c], tq);
  }
}

// -------- bias fold --------
__global__ void k_prep_bias(const float* __restrict__ st,
    const float* __restrict__ g1, const float* __restrict__ b1v,
    const float* __restrict__ wf, const float* __restrict__ wb,
    const float* __restrict__ bif, const float* __restrict__ bhf,
    const float* __restrict__ bib, const float* __restrict__ bhb,
    float* __restrict__ bef, float* __restrict__ beb){
  int id = blockIdx.x*256 + threadIdx.x;
  if (id >= 2*NPAD) return;
  int dir = id/NPAD, g = id%NPAD;
  float* be = dir? beb : bef;
  if (g >= G4){ be[g]=0.f; return; }
  const float* wih = dir? wb : wf;
  float bias = dir? (bib[g]+bhb[g]) : (bif[g]+bhf[g]);
  const float Ninv = 1.f/((float)B_*(float)LOUT);
  for (int f=0;f<NF;f++){
    float m = st[f]*Ninv;
    float var = st[NF+f]*Ninv - m*m;
    float a = g1[f]*rsqrtf(var+EPS);
    float d = b1v[f] - m*a;
    bias += d*wih[g*NF+f];
  }
  be[g] = bias;
}

// -------- pack AdaBN-folded w_ih into f16 MFMA B-fragments --------
__global__ void k_prep_wih(const float* __restrict__ st,
    const float* __restrict__ g1,
    const float* __restrict__ wf, const float* __restrict__ wb,
    _Float16* __restrict__ wT16){
  int id = blockIdx.x*256 + threadIdx.x;
  if (id >= 2*PNT*PKT*64) return;
  int lane = id & 63;
  int kt = (id>>6) & 3;
  int nt = (id>>8) % PNT;
  int dir = id / (PNT*PKT*64);
  const float* wih = dir? wb : wf;
  int n = nt*16 + (lane&15);
  int kb = kt*32 + (lane>>4)*8;
  const float Ninv = 1.f/((float)B_*(float)LOUT);
  half8 v;
  #pragma unroll
  for (int j=0;j<8;j++){
    int k = kb+j;
    float m = st[k]*Ninv;
    float var = st[NF+k]*Ninv - m*m;
    float a = g1[k]*rsqrtf(var+EPS);
    float f = (n < G4) ? wih[(size_t)n*NF + k]*a : 0.f;
    v[j] = (_Float16)f;
  }
  *(half8*)&wT16[(size_t)id*8] = v;
}

// -------- pack w_hh into f16 MFMA B-fragments --------
__global__ void k_prep_whh(const float* __restrict__ whf, const float* __restrict__ whb,
                           _Float16* __restrict__ wfrag){
  int id = blockIdx.x*256 + threadIdx.x;
  if (id >= 2*NT_*KT_*64) return;
  int lane = id & 63;
  int rest = id >> 6;
  int kt = rest % KT_;
  int nt = (rest/KT_) % NT_;
  int dir = rest / (KT_*NT_);
  const float* wh = dir? whb : whf;
  int n = nt*16 + (lane&15);
  int kb = kt*32 + (lane>>4)*8;
  half8 v;
  #pragma unroll
  for (int j=0;j<8;j++){
    int k = kb + j;
    float f = (n < G4 && k < HID) ? wh[(size_t)n*HID + k] : 0.f;
    v[j] = (_Float16)f;
  }
  *(half8*)&wfrag[(size_t)id*8] = v;
}

// ---------------- projection via f16 MFMA (unchanged) ----------------
__global__ __launch_bounds__(256) void k_proj2(const _Float16* __restrict__ y16,
    const _Float16* __restrict__ wT16,
    const float* __restrict__ bef, const float* __restrict__ beb,
    _Float16* __restrict__ pre16f, _Float16* __restrict__ pre16b,
    int t0f, int tc){
  __shared__ _Float16 Ds[128*136];
  __shared__ float bs[128];
  int dir = blockIdx.z;
  const _Float16* wfp = wT16 + (size_t)dir*PNT*PKT*64*8;
  const float* be = dir? beb : bef;
  _Float16* pre = dir? pre16b : pre16f;
  int tid = threadIdx.x, lane = tid&63, w = tid>>6;
  int trel = blockIdx.x>>2, bb = (blockIdx.x&3)*128;
  int t = dir ? (LOUT-1-t0f-trel) : (t0f+trel);
  int n0 = blockIdx.y*128;
  if (tid < 32) *(float4*)&bs[tid*4] = *(const float4*)&be[n0 + tid*4];

  f32x4 acc[2][8];
  #pragma unroll
  for (int i=0;i<2;i++)
    #pragma unroll
    for (int j=0;j<8;j++) acc[i][j] = (f32x4){0,0,0,0};

  int arow = lane&15, aq = (lane>>4)*8;
  const _Float16* a0p = y16 + ((size_t)(bb + (2*w)*16 + arow)*LOUT + t)*NF + aq;
  const _Float16* a1p = a0p + (size_t)16*LOUT*NF;
  int nb = n0 >> 4;
  #pragma unroll
  for (int kt=0; kt<PKT; kt++){
    half8 a0 = *(const half8*)(a0p + kt*32);
    half8 a1 = *(const half8*)(a1p + kt*32);
    #pragma unroll
    for (int nt=0; nt<8; nt++){
      half8 bf = *(const half8*)&wfp[(size_t)(((nb+nt)*PKT + kt)*64 + lane)*8];
      acc[0][nt] = __builtin_amdgcn_mfma_f32_16x16x32_f16(a0, bf, acc[0][nt], 0,0,0);
      acc[1][nt] = __builtin_amdgcn_mfma_f32_16x16x32_f16(a1, bf, acc[1][nt], 0,0,0);
    }
  }
  __syncthreads();
  int dcol = lane&15, dq = (lane>>4)*4;
  #pragma unroll
  for (int mi=0; mi<2; mi++){
    int rowb = (2*w+mi)*16 + dq;
    #pragma unroll
    for (int nt=0; nt<8; nt++){
      int colL = nt*16 + dcol;
      float bv = bs[colL];
      #pragma unroll
      for (int r=0;r<4;r++)
        Ds[(rowb+r)*136 + colL] = (_Float16)(acc[mi][nt][r] + bv);
    }
  }
  __syncthreads();
  int row = tid>>1, h = tid&1;
  const _Float16* src = &Ds[row*136 + h*64];
  _Float16* dst = pre + ((size_t)(trel*B_ + bb + row))*NPAD + n0 + h*64;
  #pragma unroll
  for (int qq=0; qq<8; qq++)
    *(float4*)(dst + qq*8) = *(const float4*)(src + qq*8);
}

// ---------------- recurrence v4: M=16/block, 64 blocks, coalesced LDS pre staging ----------------
// pls row stride 640 == staging map width (round-8 bug: was 616 -> row spill).
// Ordering: pls-write -> barrier1 -> cell-read; hh-write -> barrier2 -> MFMA-read.
__global__ __launch_bounds__(1024)
void k_rec4(const _Float16* __restrict__ wfrag,
            const _Float16* __restrict__ pref, const _Float16* __restrict__ preb,
            float* __restrict__ hst, float* __restrict__ cst, float* __restrict__ mst,
            float* __restrict__ pooled, int tc, int first, int last){
  int dir = blockIdx.x >> 5;
  int b0 = (blockIdx.x & 31) * 16;
  const _Float16* pre = dir? preb : pref;
  int tid = threadIdx.x;
  int lane = tid & 63, w = tid >> 6;

  __shared__ __align__(16) _Float16 hh[16][168];   // h state f16 (5376 B)
  __shared__ float dls[16][612];                   // matvec results (39168 B)
  __shared__ __align__(16) _Float16 pls[16][640];  // pre staging (20480 B)

  // ---- B fragments (weights) -> registers: waves 0-5: 3 nt, 6-15: 2 nt ----
  int cnt  = (w<6) ? 3 : 2;
  int base = (w<6) ? 3*w : 18 + 2*(w-6);
  const _Float16* wf = wfrag + (size_t)dir*NT_*KT_*64*8;
  half8 bfr[3][5];
  #pragma unroll
  for (int i=0;i<3;i++){
    #pragma unroll
    for (int kt=0;kt<KT_;kt++){
      int ntc = (i<cnt)? (base+i) : base;
      bfr[i][kt] = *(const half8*)&wf[(size_t)((ntc*KT_+kt)*64 + lane)*8];
    }
  }

  // ---- staging mapping: 1280 half8 chunks = 16 rows x 80 chunks ----
  int srow0 = tid/80,          scol0 = (tid%80)*8;
  int srow1 = (tid+1024)/80,   scol1 = ((tid+1024)%80)*8;
  bool s2 = tid < 256;

  // ---- cell-unit mapping: 3 ids per thread over 16x152 ----
  int bl[3], uu[3];
  bool valid[3];
  #pragma unroll
  for (int k=0;k<3;k++){
    int id = tid + k*1024;
    int b = id / HSTR, u = id - b*HSTR;
    bl[k]=b; uu[k]=u;
    valid[k] = (id < 16*HSTR) && (u < HID);
  }

  // ---- init state + stage pre[0] ----
  for (int i=tid; i<16*168; i+=1024) (&hh[0][0])[i] = (_Float16)0.f;
  float c[3], m[3], hlast[3];
  #pragma unroll
  for (int k=0;k<3;k++){ c[k]=0.f; m[k]=-1e30f; hlast[k]=0.f; }
  if (!first){
    #pragma unroll
    for (int k=0;k<3;k++){
      if (valid[k]){
        size_t gi = ((size_t)(dir*B_ + b0 + bl[k]))*HSTR + uu[k];
        c[k]=cst[gi]; m[k]=mst[gi];
        float hv = hst[gi]; hlast[k]=hv;
        hh[bl[k]][uu[k]] = (_Float16)hv;
      }
    }
  }
  {
    half8 s0 = *(const half8*)(pre + ((size_t)(b0 + srow0))*NPAD + scol0);
    *(half8*)&pls[srow0][scol0] = s0;
    if (s2){
      half8 s1 = *(const half8*)(pre + ((size_t)(b0 + srow1))*NPAD + scol1);
      *(half8*)&pls[srow1][scol1] = s1;
    }
  }
  __syncthreads();

  int arow = lane & 15;
  int koff = (lane>>4)*8;
  int drow = (lane>>4)*4;

  for (int t=0; t<tc; t++){
    // 1. issue prefetch of pre[t+1] -> regs (coalesced half8)
    half8 s0, s1;
    bool ld = (t+1 < tc);
    if (ld){
      size_t rbase = (size_t)(t+1)*B_ + b0;
      s0 = *(const half8*)(pre + (rbase + srow0)*NPAD + scol0);
      if (s2) s1 = *(const half8*)(pre + (rbase + srow1)*NPAD + scol1);
    }
    // 2. MFMA phase
    f32x4 acc0={0,0,0,0}, acc1={0,0,0,0}, acc2={0,0,0,0};
    #pragma unroll
    for (int kt=0; kt<KT_; kt++){
      half8 a = *(const half8*)&hh[arow][kt*32 + koff];
      acc0 = __builtin_amdgcn_mfma_f32_16x16x32_f16(a, bfr[0][kt], acc0, 0,0,0);
      acc1 = __builtin_amdgcn_mfma_f32_16x16x32_f16(a, bfr[1][kt], acc1, 0,0,0);
      if (cnt>2) acc2 = __builtin_amdgcn_mfma_f32_16x16x32_f16(a, bfr[2][kt], acc2, 0,0,0);
    }
    {
      int col0 = (base+0)*16 + (lane&15);
      int col1 = (base+1)*16 + (lane&15);
      #pragma unroll
      for (int r=0;r<4;r++){ dls[drow+r][col0]=acc0[r]; dls[drow+r][col1]=acc1[r]; }
      if (cnt>2){
        int col2 = (base+2)*16 + (lane&15);
        #pragma unroll
        for (int r=0;r<4;r++) dls[drow+r][col2]=acc2[r];
      }
    }
    __syncthreads();   // barrier1: dls ready; pls holds pre[t]
    // 3. cell phase
    #pragma unroll
    for (int k=0;k<3;k++){
      if (valid[k]){
        int b=bl[k], u=uu[k];
        float pi = dls[b][u]      + (float)pls[b][u];
        float pfg= dls[b][u+150]  + (float)pls[b][u+150];
        float pg = dls[b][u+300]  + (float)pls[b][u+300];
        float po = dls[b][u+450]  + (float)pls[b][u+450];
        float ig=hsig(pi), fg=hsig(pfg), og=hsig(po), gg=ftanh(pg);
        c[k] = fg*c[k] + ig*gg;
        float hv = og*ftanh(c[k]);
        m[k] = fmaxf(m[k], hv);
        hlast[k] = hv;
        hh[b][u] = (_Float16)hv;
      }
    }
    __syncthreads();   // barrier2: hh ready; pls free to overwrite
    // 4. write prefetched regs -> pls (overlaps next MFMA phase)
    if (ld){
      *(half8*)&pls[srow0][scol0] = s0;
      if (s2) *(half8*)&pls[srow1][scol1] = s1;
    }
  }

  #pragma unroll
  for (int k=0;k<3;k++){
    if (valid[k]){
      size_t gi = ((size_t)(dir*B_ + b0 + bl[k]))*HSTR + uu[k];
      cst[gi]=c[k]; mst[gi]=m[k]; hst[gi]=hlast[k];
      if (last) pooled[(size_t)(b0+bl[k])*300 + dir*HID + uu[k]] = m[k];
    }
  }
}

// ---------------- tails ----------------
__global__ void k_stats2(const float* __restrict__ pooled,
    const float* __restrict__ g2, const float* __restrict__ b2,
    float* __restrict__ a2, float* __restrict__ d2){
  int f = threadIdx.x;
  if (f >= 300) return;
  float s=0.f,q=0.f;
  for (int b=0;b<B_;b++){ float v = pooled[(size_t)b*300+f]; s+=v; q+=v*v; }
  float m = s*(1.f/B_), var = q*(1.f/B_) - m*m;
  float a = g2[f]*rsqrtf(var+EPS);
  a2[f]=a; d2[f]=b2[f]-m*a;
}

__global__ void k_fc1(const float* __restrict__ pooled,
    const float* __restrict__ a2, const float* __restrict__ d2,
    const float* __restrict__ w1, const float* __restrict__ fb1,
    float* __restrict__ z1){
  int o = blockIdx.x*256 + threadIdx.x;
  if (o >= B_*50) return;
  int b = o/50, j = o%50;
  float acc = fb1[j];
  for (int f=0;f<300;f++)
    acc += (a2[f]*pooled[(size_t)b*300+f] + d2[f]) * w1[j*300+f];
  z1[o] = fmaxf(acc,0.f);
}

__global__ void k_stats3(const float* __restrict__ z1,
    const float* __restrict__ g3, const float* __restrict__ b3,
    float* __restrict__ a3, float* __restrict__ d3){
  int f = threadIdx.x;
  if (f >= 50) return;
  float s=0.f,q=0.f;
  for (int b=0;b<B_;b++){ float v = z1[(size_t)b*50+f]; s+=v; q+=v*v; }
  float m = s*(1.f/B_), var = q*(1.f/B_) - m*m;
  float a = g3[f]*rsqrtf(var+EPS);
  a3[f]=a; d3[f]=b3[f]-m*a;
}

__global__ void k_fc2(const float* __restrict__ z1,
    const float* __restrict__ a3, const float* __restrict__ d3,
    const float* __restrict__ w2, const float* __restrict__ fb2,
    float* __restrict__ out){
  int b = blockIdx.x;
  int t = threadIdx.x;
  __shared__ float zl[50];
  __shared__ float lg[10];
  if (t<50) zl[t] = a3[t]*z1[(size_t)b*50+t] + d3[t];
  __syncthreads();
  if (t<10){
    float acc = fb2[t];
    for (int j=0;j<50;j++) acc += zl[j]*w2[t*50+j];
    lg[t]=acc;
  }
  __syncthreads();
  if (t<10){
    float m = lg[0];
    #pragma unroll
    for (int i=1;i<10;i++) m = fmaxf(m,lg[i]);
    float s = 0.f;
    #pragma unroll
    for (int i=0;i<10;i++) s += expf(lg[i]-m);
    out[(size_t)b*10+t] = expf(lg[t]-m)/s;
  }
}

extern "C" void kernel_launch(void* const* d_in, const int* in_sizes, int n_in,
                              void* d_out, int out_size, void* d_ws, size_t ws_size,
                              hipStream_t stream) {
  const float* x    = (const float*)d_in[0];
  const float* cw   = (const float*)d_in[1];
  const float* cb   = (const float*)d_in[2];
  const float* g1   = (const float*)d_in[3];
  const float* b1v  = (const float*)d_in[4];
  const float* wihf = (const float*)d_in[5];
  const float* whhf = (const float*)d_in[6];
  const float* bihf = (const float*)d_in[7];
  const float* bhhf = (const float*)d_in[8];
  const float* wihb = (const float*)d_in[9];
  const float* whhb = (const float*)d_in[10];
  const float* bihb = (const float*)d_in[11];
  const float* bhhb = (const float*)d_in[12];
  const float* g2   = (const float*)d_in[13];
  const float* b2   = (const float*)d_in[14];
  const float* w1   = (const float*)d_in[15];
  const float* fb1  = (const float*)d_in[16];
  const float* g3   = (const float*)d_in[17];
  const float* b3   = (const float*)d_in[18];
  const float* w2   = (const float*)d_in[19];
  const float* fb2  = (const float*)d_in[20];
  float* out = (float*)d_out;

  uint8_t* base = (uint8_t*)d_ws;
  size_t off = 0;
  auto allocB = [&](size_t nbytes)->uint8_t*{
    uint8_t* p = base + off;
    off = (off + nbytes + 255) & ~(size_t)255;
    return p;
  };
  _Float16* y16   = (_Float16*)allocB((size_t)B_*LOUT*NF*2);
  float* st       = (float*)allocB(256*4);
  _Float16* wT16  = (_Float16*)allocB((size_t)2*PNT*PKT*64*8*2);
  float* bef      = (float*)allocB(NPAD*4);
  float* beb      = (float*)allocB(NPAD*4);
  _Float16* wfrag = (_Float16*)allocB((size_t)2*NT_*KT_*64*8*2);
  float* hst      = (float*)allocB((size_t)2*B_*HSTR*4);
  float* cst      = (float*)allocB((size_t)2*B_*HSTR*4);
  float* mst      = (float*)allocB((size_t)2*B_*HSTR*4);
  float* pooled   = (float*)allocB((size_t)B_*300*4);
  float* a2       = (float*)allocB(320*4);
  float* d2       = (float*)allocB(320*4);
  float* z1       = (float*)allocB((size_t)B_*50*4);
  float* a3       = (float*)allocB(64*4);
  float* d3       = (float*)allocB(64*4);
  size_t fixedEnd = off;

  size_t per_t = (size_t)2*B_*NPAD*2;   // both dirs, f16
  size_t avail = (ws_size > fixedEnd + 4096) ? (ws_size - fixedEnd - 4096) : 0;
  int tcmax = (int)(avail / per_t);
  if (tcmax < 1) tcmax = 1;
  if (tcmax > LOUT) tcmax = LOUT;
  int nch = (LOUT + tcmax - 1) / tcmax;
  int TC = (LOUT + nch - 1) / nch;
  _Float16* pre16f = (_Float16*)allocB((size_t)TC*B_*NPAD*2);
  _Float16* pre16b = (_Float16*)allocB((size_t)TC*B_*NPAD*2);

  hipMemsetAsync(st, 0, 256*4, stream);
  k_conv2<<<B_, 512, 0, stream>>>(x, cw, cb, y16, st);
  k_prep_bias<<<(2*NPAD+255)/256, 256, 0, stream>>>(st, g1, b1v, wihf, wihb,
                                                    bihf, bhhf, bihb, bhhb, bef, beb);
  k_prep_wih<<<(2*PNT*PKT*64+255)/256, 256, 0, stream>>>(st, g1, wihf, wihb, wT16);
  k_prep_whh<<<(2*NT_*KT_*64+255)/256, 256, 0, stream>>>(whhf, whhb, wfrag);

  int t0 = 0; int first = 1;
  while (t0 < LOUT){
    int tc = (TC < LOUT - t0) ? TC : (LOUT - t0);
    int lastc = (t0 + tc >= LOUT) ? 1 : 0;
    k_proj2<<<dim3(tc*4, 5, 2), 256, 0, stream>>>(y16, wT16, bef, beb,
                                                  pre16f, pre16b, t0, tc);
    k_rec4<<<64, 1024, 0, stream>>>(wfrag, pre16f, pre16b,
                                    hst, cst, mst, pooled, tc, first, lastc);
    t0 += tc; first = 0;
  }
  k_stats2<<<1, 320, 0, stream>>>(pooled, g2, b2, a2, d2);
  k_fc1<<<(B_*50+255)/256, 256, 0, stream>>>(pooled, a2, d2, w1, fb1, z1);
  k_stats3<<<1, 64, 0, stream>>>(z1, g3, b3, a3, d3);
  k_fc2<<<B_, 64, 0, stream>>>(z1, a3, d3, w2, fb2, out);
}

// Round 10
// 1126.944 us; speedup vs baseline: 1.8441x; 1.0453x over previous
//
#include <hip/hip_runtime.h>
#include <math.h>

#define B_   512
#define T_   800
#define FIN  3
#define NF   128
#define KW   15
#define HID  150
#define LOUT 393
#define G4   600
#define NPAD 640
#define EPS  1e-5f

#define NT_  38          // whh N tiles of 16 over 608 (interleaved gate order)
#define KT_  5           // whh K tiles of 32 over 160
#define HSTR 152
#define PNT  40          // wih N tiles of 16 over 640
#define PKT  4           // wih K tiles of 32 over 128

typedef _Float16 half8 __attribute__((ext_vector_type(8)));
typedef _Float16 half4 __attribute__((ext_vector_type(4)));
typedef float f32x4 __attribute__((ext_vector_type(4)));

__device__ __forceinline__ float hsig(float x){ return fminf(fmaxf(0.2f*x+0.5f,0.f),1.f); }
__device__ __forceinline__ float ftanh(float x){ float e=__expf(2.f*x); return 1.f - 2.f/(e+1.f); }

// ------- conv + relu + maxpool2 + f16 store + AdaBN1 stats (fused) -------
__global__ __launch_bounds__(512) void k_conv2(const float* __restrict__ x,
        const float* __restrict__ cw, const float* __restrict__ cb,
        _Float16* __restrict__ y16, float* __restrict__ st){
  __shared__ float xs[FIN][800];
  __shared__ float wl[NF*FIN*KW];
  __shared__ float rs[4][128], rq[4][128];
  int tid = threadIdx.x;
  int b = blockIdx.x;
  for (int i=tid;i<FIN*800;i+=512) (&xs[0][0])[i] = x[(size_t)b*(FIN*T_) + i];
  for (int i=tid;i<NF*FIN*KW;i+=512) wl[i]=cw[i];
  __syncthreads();
  int c = tid & 127, li = tid >> 7;
  float wr[FIN*KW];
  #pragma unroll
  for (int i=0;i<FIN*KW;i++) wr[i]=wl[c*FIN*KW+i];
  float cbv = cb[c];
  float s=0.f, q=0.f;
  for (int l=li; l<LOUT; l+=4){
    float a0=0.f, a1=0.f;
    #pragma unroll
    for (int f=0;f<FIN;f++){
      const float2* xp = (const float2*)&xs[f][0] + l;
      float xv[16];
      #pragma unroll
      for (int p=0;p<8;p++){ float2 v=xp[p]; xv[2*p]=v.x; xv[2*p+1]=v.y; }
      #pragma unroll
      for (int k=0;k<KW;k++){ float w=wr[f*KW+k]; a0 += w*xv[k]; a1 += w*xv[k+1]; }
    }
    float v = fmaxf(fmaxf(a0,a1)+cbv, 0.f);
    y16[((size_t)b*LOUT + l)*NF + c] = (_Float16)v;
    s += v; q += v*v;
  }
  rs[li][c]=s; rq[li][c]=q;
  __syncthreads();
  if (tid < 128){
    float ts = rs[0][c]+rs[1][c]+rs[2][c]+rs[3][c];
    float tq = rq[0][c]+rq[1][c]+rq[2][c]+rq[3][c];
    atomicAdd(&st[c], ts);
    atomicAdd(&st[128+c], tq);
  }
}

// -------- bias fold (gate-interleaved output order) --------
__global__ void k_prep_bias(const float* __restrict__ st,
    const float* __restrict__ g1, const float* __restrict__ b1v,
    const float* __restrict__ wf, const float* __restrict__ wb,
    const float* __restrict__ bif, const float* __restrict__ bhf,
    const float* __restrict__ bib, const float* __restrict__ bhb,
    float* __restrict__ bef, float* __restrict__ beb){
  int id = blockIdx.x*256 + threadIdx.x;
  if (id >= 2*NPAD) return;
  int dir = id/NPAD, g = id%NPAD;
  float* be = dir? beb : bef;
  if (g >= G4){ be[g]=0.f; return; }
  int src = (g&3)*HID + (g>>2);          // interleave: col 4u+gate <- row gate*150+u
  const float* wih = dir? wb : wf;
  float bias = dir? (bib[src]+bhb[src]) : (bif[src]+bhf[src]);
  const float Ninv = 1.f/((float)B_*(float)LOUT);
  for (int f=0;f<NF;f++){
    float m = st[f]*Ninv;
    float var = st[NF+f]*Ninv - m*m;
    float a = g1[f]*rsqrtf(var+EPS);
    float d = b1v[f] - m*a;
    bias += d*wih[(size_t)src*NF+f];
  }
  be[g] = bias;
}

// -------- pack AdaBN-folded w_ih into f16 MFMA fragments (interleaved cols) --------
__global__ void k_prep_wih(const float* __restrict__ st,
    const float* __restrict__ g1,
    const float* __restrict__ wf, const float* __restrict__ wb,
    _Float16* __restrict__ wT16){
  int id = blockIdx.x*256 + threadIdx.x;
  if (id >= 2*PNT*PKT*64) return;
  int lane = id & 63;
  int kt = (id>>6) & 3;
  int nt = (id>>8) % PNT;
  int dir = id / (PNT*PKT*64);
  const float* wih = dir? wb : wf;
  int n = nt*16 + (lane&15);
  int src = (n&3)*HID + (n>>2);
  int kb = kt*32 + (lane>>4)*8;
  const float Ninv = 1.f/((float)B_*(float)LOUT);
  half8 v;
  #pragma unroll
  for (int j=0;j<8;j++){
    int k = kb+j;
    float m = st[k]*Ninv;
    float var = st[NF+k]*Ninv - m*m;
    float a = g1[k]*rsqrtf(var+EPS);
    float f = (n < G4) ? wih[(size_t)src*NF + k]*a : 0.f;
    v[j] = (_Float16)f;
  }
  *(half8*)&wT16[(size_t)id*8] = v;
}

// -------- pack w_hh into f16 MFMA fragments (interleaved cols) --------
__global__ void k_prep_whh(const float* __restrict__ whf, const float* __restrict__ whb,
                           _Float16* __restrict__ wfrag){
  int id = blockIdx.x*256 + threadIdx.x;
  if (id >= 2*NT_*KT_*64) return;
  int lane = id & 63;
  int rest = id >> 6;
  int kt = rest % KT_;
  int nt = (rest/KT_) % NT_;
  int dir = rest / (KT_*NT_);
  const float* wh = dir? whb : whf;
  int n = nt*16 + (lane&15);
  int src = (n&3)*HID + (n>>2);
  int kb = kt*32 + (lane>>4)*8;
  half8 v;
  #pragma unroll
  for (int j=0;j<8;j++){
    int k = kb + j;
    float f = (n < G4 && k < HID) ? wh[(size_t)src*HID + k] : 0.f;
    v[j] = (_Float16)f;
  }
  *(half8*)&wfrag[(size_t)id*8] = v;
}

// ---------------- projection via f16 MFMA (unchanged — permutation-transparent) ----------------
__global__ __launch_bounds__(256) void k_proj2(const _Float16* __restrict__ y16,
    const _Float16* __restrict__ wT16,
    const float* __restrict__ bef, const float* __restrict__ beb,
    _Float16* __restrict__ pre16f, _Float16* __restrict__ pre16b,
    int t0f, int tc){
  __shared__ _Float16 Ds[128*136];
  __shared__ float bs[128];
  int dir = blockIdx.z;
  const _Float16* wfp = wT16 + (size_t)dir*PNT*PKT*64*8;
  const float* be = dir? beb : bef;
  _Float16* pre = dir? pre16b : pre16f;
  int tid = threadIdx.x, lane = tid&63, w = tid>>6;
  int trel = blockIdx.x>>2, bb = (blockIdx.x&3)*128;
  int t = dir ? (LOUT-1-t0f-trel) : (t0f+trel);
  int n0 = blockIdx.y*128;
  if (tid < 32) *(float4*)&bs[tid*4] = *(const float4*)&be[n0 + tid*4];

  f32x4 acc[2][8];
  #pragma unroll
  for (int i=0;i<2;i++)
    #pragma unroll
    for (int j=0;j<8;j++) acc[i][j] = (f32x4){0,0,0,0};

  int arow = lane&15, aq = (lane>>4)*8;
  const _Float16* a0p = y16 + ((size_t)(bb + (2*w)*16 + arow)*LOUT + t)*NF + aq;
  const _Float16* a1p = a0p + (size_t)16*LOUT*NF;
  int nb = n0 >> 4;
  #pragma unroll
  for (int kt=0; kt<PKT; kt++){
    half8 a0 = *(const half8*)(a0p + kt*32);
    half8 a1 = *(const half8*)(a1p + kt*32);
    #pragma unroll
    for (int nt=0; nt<8; nt++){
      half8 bf = *(const half8*)&wfp[(size_t)(((nb+nt)*PKT + kt)*64 + lane)*8];
      acc[0][nt] = __builtin_amdgcn_mfma_f32_16x16x32_f16(a0, bf, acc[0][nt], 0,0,0);
      acc[1][nt] = __builtin_amdgcn_mfma_f32_16x16x32_f16(a1, bf, acc[1][nt], 0,0,0);
    }
  }
  __syncthreads();
  int dcol = lane&15, dq = (lane>>4)*4;
  #pragma unroll
  for (int mi=0; mi<2; mi++){
    int rowb = (2*w+mi)*16 + dq;
    #pragma unroll
    for (int nt=0; nt<8; nt++){
      int colL = nt*16 + dcol;
      float bv = bs[colL];
      #pragma unroll
      for (int r=0;r<4;r++)
        Ds[(rowb+r)*136 + colL] = (_Float16)(acc[mi][nt][r] + bv);
    }
  }
  __syncthreads();
  int row = tid>>1, h = tid&1;
  const _Float16* src = &Ds[row*136 + h*64];
  _Float16* dst = pre + ((size_t)(trel*B_ + bb + row))*NPAD + n0 + h*64;
  #pragma unroll
  for (int qq=0; qq<8; qq++)
    *(float4*)(dst + qq*8) = *(const float4*)(src + qq*8);
}

// ---------------- recurrence v5: swapped-operand MFMA (D = W x H^T), lane-local cell ----------------
// Gate-interleaved cols: lane holds all 4 gates of one (unit,batch) in acc[0..3].
// No dls array. hh + pls double-buffered -> ONE barrier per step.
__global__ __launch_bounds__(1024)
void k_rec5(const _Float16* __restrict__ wfrag,
            const _Float16* __restrict__ pref, const _Float16* __restrict__ preb,
            float* __restrict__ hst, float* __restrict__ cst, float* __restrict__ mst,
            float* __restrict__ pooled, int tc, int first, int last){
  int dir = blockIdx.x >> 5;
  int b0 = (blockIdx.x & 31) * 16;
  const _Float16* pre = dir? preb : pref;
  int tid = threadIdx.x;
  int lane = tid & 63, w = tid >> 6;

  __shared__ __align__(16) _Float16 hh[2][16][168];   // 10752 B
  __shared__ __align__(16) _Float16 pls[2][16][640];  // 40960 B

  // ---- weight fragments (A-operand) -> registers/AGPRs: waves 0-5: 3 nt, 6-15: 2 nt ----
  int cnt  = (w<6) ? 3 : 2;
  int base = (w<6) ? 3*w : 18 + 2*(w-6);
  const _Float16* wf = wfrag + (size_t)dir*NT_*KT_*64*8;
  half8 bfr[3][5];
  #pragma unroll
  for (int i=0;i<3;i++){
    #pragma unroll
    for (int kt=0;kt<KT_;kt++){
      int ntc = (i<cnt)? (base+i) : base;
      bfr[i][kt] = *(const half8*)&wf[(size_t)((ntc*KT_+kt)*64 + lane)*8];
    }
  }

  // ---- lane-local cell ownership: batch = lane&15, uo per ntile ----
  int batch = lane & 15;
  int uo[3]; bool uv[3];
  #pragma unroll
  for (int i=0;i<3;i++){
    uo[i] = (base+i)*4 + (lane>>4);
    uv[i] = (i<cnt) && (uo[i] < HID);
  }

  // ---- staging mapping: 1280 half8 chunks = 16 rows x 80 chunks ----
  int srow0 = tid/80,        scol0 = (tid%80)*8;
  int srow1 = (tid+1024)/80, scol1 = ((tid+1024)%80)*8;
  bool s2 = tid < 256;

  // ---- init: zero hh (both buffers incl k-pad), load state, stage pre[0] ----
  for (int i=tid; i<2*16*168; i+=1024) (&hh[0][0][0])[i] = (_Float16)0.f;
  float c[3], m[3], hl[3];
  #pragma unroll
  for (int i=0;i<3;i++){ c[i]=0.f; m[i]=-1e30f; hl[i]=0.f; }
  __syncthreads();   // zeros complete before state writes land in hh[0]
  if (!first){
    #pragma unroll
    for (int i=0;i<3;i++){
      if (uv[i]){
        size_t gi = ((size_t)(dir*B_ + b0 + batch))*HSTR + uo[i];
        c[i]=cst[gi]; m[i]=mst[gi]; hl[i]=hst[gi];
        hh[0][batch][uo[i]] = (_Float16)hl[i];
      }
    }
  }
  {
    half8 s0 = *(const half8*)(pre + ((size_t)(b0 + srow0))*NPAD + scol0);
    *(half8*)&pls[0][srow0][scol0] = s0;
    if (s2){
      half8 s1 = *(const half8*)(pre + ((size_t)(b0 + srow1))*NPAD + scol1);
      *(half8*)&pls[0][srow1][scol1] = s1;
    }
  }
  __syncthreads();

  int cur = 0;
  for (int t=0; t<tc; t++){
    int nxt = cur ^ 1;
    // 1. issue prefetch of pre[t+1] -> regs
    half8 s0, s1;
    bool ld = (t+1 < tc);
    if (ld){
      size_t rbase = (size_t)(t+1)*B_ + b0;
      s0 = *(const half8*)(pre + (rbase + srow0)*NPAD + scol0);
      if (s2) s1 = *(const half8*)(pre + (rbase + srow1)*NPAD + scol1);
    }
    // 2. MFMA: D[gate_col][batch] = W x H^T  (weights as A, h as B)
    f32x4 acc0={0,0,0,0}, acc1={0,0,0,0}, acc2={0,0,0,0};
    #pragma unroll
    for (int kt=0; kt<KT_; kt++){
      half8 a = *(const half8*)&hh[cur][batch][kt*32 + (lane>>4)*8];
      acc0 = __builtin_amdgcn_mfma_f32_16x16x32_f16(bfr[0][kt], a, acc0, 0,0,0);
      acc1 = __builtin_amdgcn_mfma_f32_16x16x32_f16(bfr[1][kt], a, acc1, 0,0,0);
      if (cnt>2) acc2 = __builtin_amdgcn_mfma_f32_16x16x32_f16(bfr[2][kt], a, acc2, 0,0,0);
    }
    // 3. cell: fully lane-local (acc[r] = gate r of unit uo[i] for this batch)
    #define CELL(ACC, I)                                                     \
    if (uv[I]){                                                              \
      half4 pv = *(const half4*)&pls[cur][batch][4*uo[I]];                   \
      float xi = ACC[0] + (float)pv[0];                                      \
      float xf = ACC[1] + (float)pv[1];                                      \
      float xg = ACC[2] + (float)pv[2];                                      \
      float xo = ACC[3] + (float)pv[3];                                      \
      float ig=hsig(xi), fg=hsig(xf), og=hsig(xo), gg=ftanh(xg);             \
      c[I] = fg*c[I] + ig*gg;                                                \
      float hv = og*ftanh(c[I]);                                             \
      m[I] = fmaxf(m[I], hv);                                                \
      hl[I] = hv;                                                            \
      hh[nxt][batch][uo[I]] = (_Float16)hv;                                  \
    }
    CELL(acc0, 0)
    CELL(acc1, 1)
    CELL(acc2, 2)
    #undef CELL
    // 4. write prefetched pre -> pls[nxt] (not read until after the barrier)
    if (ld){
      *(half8*)&pls[nxt][srow0][scol0] = s0;
      if (s2) *(half8*)&pls[nxt][srow1][scol1] = s1;
    }
    __syncthreads();   // hh[nxt] + pls[nxt] ready for step t+1
    cur = nxt;
  }

  #pragma unroll
  for (int i=0;i<3;i++){
    if (uv[i]){
      size_t gi = ((size_t)(dir*B_ + b0 + batch))*HSTR + uo[i];
      cst[gi]=c[i]; mst[gi]=m[i]; hst[gi]=hl[i];
      if (last) pooled[(size_t)(b0+batch)*300 + dir*HID + uo[i]] = m[i];
    }
  }
}

// ---------------- tails ----------------
__global__ void k_stats2(const float* __restrict__ pooled,
    const float* __restrict__ g2, const float* __restrict__ b2,
    float* __restrict__ a2, float* __restrict__ d2){
  int f = threadIdx.x;
  if (f >= 300) return;
  float s=0.f,q=0.f;
  for (int b=0;b<B_;b++){ float v = pooled[(size_t)b*300+f]; s+=v; q+=v*v; }
  float m = s*(1.f/B_), var = q*(1.f/B_) - m*m;
  float a = g2[f]*rsqrtf(var+EPS);
  a2[f]=a; d2[f]=b2[f]-m*a;
}

__global__ void k_fc1(const float* __restrict__ pooled,
    const float* __restrict__ a2, const float* __restrict__ d2,
    const float* __restrict__ w1, const float* __restrict__ fb1,
    float* __restrict__ z1){
  int o = blockIdx.x*256 + threadIdx.x;
  if (o >= B_*50) return;
  int b = o/50, j = o%50;
  float acc = fb1[j];
  for (int f=0;f<300;f++)
    acc += (a2[f]*pooled[(size_t)b*300+f] + d2[f]) * w1[j*300+f];
  z1[o] = fmaxf(acc,0.f);
}

__global__ void k_stats3(const float* __restrict__ z1,
    const float* __restrict__ g3, const float* __restrict__ b3,
    float* __restrict__ a3, float* __restrict__ d3){
  int f = threadIdx.x;
  if (f >= 50) return;
  float s=0.f,q=0.f;
  for (int b=0;b<B_;b++){ float v = z1[(size_t)b*50+f]; s+=v; q+=v*v; }
  float m = s*(1.f/B_), var = q*(1.f/B_) - m*m;
  float a = g3[f]*rsqrtf(var+EPS);
  a3[f]=a; d3[f]=b3[f]-m*a;
}

__global__ void k_fc2(const float* __restrict__ z1,
    const float* __restrict__ a3, const float* __restrict__ d3,
    const float* __restrict__ w2, const float* __restrict__ fb2,
    float* __restrict__ out){
  int b = blockIdx.x;
  int t = threadIdx.x;
  __shared__ float zl[50];
  __shared__ float lg[10];
  if (t<50) zl[t] = a3[t]*z1[(size_t)b*50+t] + d3[t];
  __syncthreads();
  if (t<10){
    float acc = fb2[t];
    for (int j=0;j<50;j++) acc += zl[j]*w2[t*50+j];
    lg[t]=acc;
  }
  __syncthreads();
  if (t<10){
    float m = lg[0];
    #pragma unroll
    for (int i=1;i<10;i++) m = fmaxf(m,lg[i]);
    float s = 0.f;
    #pragma unroll
    for (int i=0;i<10;i++) s += expf(lg[i]-m);
    out[(size_t)b*10+t] = expf(lg[t]-m)/s;
  }
}

extern "C" void kernel_launch(void* const* d_in, const int* in_sizes, int n_in,
                              void* d_out, int out_size, void* d_ws, size_t ws_size,
                              hipStream_t stream) {
  const float* x    = (const float*)d_in[0];
  const float* cw   = (const float*)d_in[1];
  const float* cb   = (const float*)d_in[2];
  const float* g1   = (const float*)d_in[3];
  const float* b1v  = (const float*)d_in[4];
  const float* wihf = (const float*)d_in[5];
  const float* whhf = (const float*)d_in[6];
  const float* bihf = (const float*)d_in[7];
  const float* bhhf = (const float*)d_in[8];
  const float* wihb = (const float*)d_in[9];
  const float* whhb = (const float*)d_in[10];
  const float* bihb = (const float*)d_in[11];
  const float* bhhb = (const float*)d_in[12];
  const float* g2   = (const float*)d_in[13];
  const float* b2   = (const float*)d_in[14];
  const float* w1   = (const float*)d_in[15];
  const float* fb1  = (const float*)d_in[16];
  const float* g3   = (const float*)d_in[17];
  const float* b3   = (const float*)d_in[18];
  const float* w2   = (const float*)d_in[19];
  const float* fb2  = (const float*)d_in[20];
  float* out = (float*)d_out;

  uint8_t* base = (uint8_t*)d_ws;
  size_t off = 0;
  auto allocB = [&](size_t nbytes)->uint8_t*{
    uint8_t* p = base + off;
    off = (off + nbytes + 255) & ~(size_t)255;
    return p;
  };
  _Float16* y16   = (_Float16*)allocB((size_t)B_*LOUT*NF*2);
  float* st       = (float*)allocB(256*4);
  _Float16* wT16  = (_Float16*)allocB((size_t)2*PNT*PKT*64*8*2);
  float* bef      = (float*)allocB(NPAD*4);
  float* beb      = (float*)allocB(NPAD*4);
  _Float16* wfrag = (_Float16*)allocB((size_t)2*NT_*KT_*64*8*2);
  float* hst      = (float*)allocB((size_t)2*B_*HSTR*4);
  float* cst      = (float*)allocB((size_t)2*B_*HSTR*4);
  float* mst      = (float*)allocB((size_t)2*B_*HSTR*4);
  float* pooled   = (float*)allocB((size_t)B_*300*4);
  float* a2       = (float*)allocB(320*4);
  float* d2       = (float*)allocB(320*4);
  float* z1       = (float*)allocB((size_t)B_*50*4);
  float* a3       = (float*)allocB(64*4);
  float* d3       = (float*)allocB(64*4);
  size_t fixedEnd = off;

  size_t per_t = (size_t)2*B_*NPAD*2;   // both dirs, f16
  size_t avail = (ws_size > fixedEnd + 4096) ? (ws_size - fixedEnd - 4096) : 0;
  int tcmax = (int)(avail / per_t);
  if (tcmax < 1) tcmax = 1;
  if (tcmax > LOUT) tcmax = LOUT;
  int nch = (LOUT + tcmax - 1) / tcmax;
  int TC = (LOUT + nch - 1) / nch;
  _Float16* pre16f = (_Float16*)allocB((size_t)TC*B_*NPAD*2);
  _Float16* pre16b = (_Float16*)allocB((size_t)TC*B_*NPAD*2);

  hipMemsetAsync(st, 0, 256*4, stream);
  k_conv2<<<B_, 512, 0, stream>>>(x, cw, cb, y16, st);
  k_prep_bias<<<(2*NPAD+255)/256, 256, 0, stream>>>(st, g1, b1v, wihf, wihb,
                                                    bihf, bhhf, bihb, bhhb, bef, beb);
  k_prep_wih<<<(2*PNT*PKT*64+255)/256, 256, 0, stream>>>(st, g1, wihf, wihb, wT16);
  k_prep_whh<<<(2*NT_*KT_*64+255)/256, 256, 0, stream>>>(whhf, whhb, wfrag);

  int t0 = 0; int first = 1;
  while (t0 < LOUT){
    int tc = (TC < LOUT - t0) ? TC : (LOUT - t0);
    int lastc = (t0 + tc >= LOUT) ? 1 : 0;
    k_proj2<<<dim3(tc*4, 5, 2), 256, 0, stream>>>(y16, wT16, bef, beb,
                                                  pre16f, pre16b, t0, tc);
    k_rec5<<<64, 1024, 0, stream>>>(wfrag, pre16f, pre16b,
                                    hst, cst, mst, pooled, tc, first, lastc);
    t0 += tc; first = 0;
  }
  k_stats2<<<1, 320, 0, stream>>>(pooled, g2, b2, a2, d2);
  k_fc1<<<(B_*50+255)/256, 256, 0, stream>>>(pooled, a2, d2, w1, fb1, z1);
  k_stats3<<<1, 64, 0, stream>>>(z1, g3, b3, a3, d3);
  k_fc2<<<B_, 64, 0, stream>>>(z1, a3, d3, w2, fb2, out);
}

// Round 11
// 1103.790 us; speedup vs baseline: 1.8828x; 1.0210x over previous
//
#include <hip/hip_runtime.h>
#include <math.h>

#define B_   512
#define T_   800
#define FIN  3
#define NF   128
#define KW   15
#define HID  150
#define LOUT 393
#define G4   600
#define NPAD 640
#define EPS  1e-5f

#define NT_  38          // whh N tiles of 16 over 608 (interleaved gate order)
#define KT_  5           // whh K tiles of 32 over 160
#define HSTR 152
#define PNT  40          // wih N tiles of 16 over 640
#define PKT  4           // wih K tiles of 32 over 128
#define PSTR 648         // pls row stride: 648*2B=1296B -> bank coeff 4 -> 2-way (free)

typedef _Float16 half8 __attribute__((ext_vector_type(8)));
typedef _Float16 half4 __attribute__((ext_vector_type(4)));
typedef float f32x4 __attribute__((ext_vector_type(4)));

__device__ __forceinline__ float hsig(float x){ return fminf(fmaxf(0.2f*x+0.5f,0.f),1.f); }
__device__ __forceinline__ float ftanh(float x){ float e=__expf(2.f*x); return 1.f - 2.f/(e+1.f); }

// ------- conv + relu + maxpool2 + f16 store + AdaBN1 stats (fused) -------
__global__ __launch_bounds__(512) void k_conv2(const float* __restrict__ x,
        const float* __restrict__ cw, const float* __restrict__ cb,
        _Float16* __restrict__ y16, float* __restrict__ st){
  __shared__ float xs[FIN][800];
  __shared__ float wl[NF*FIN*KW];
  __shared__ float rs[4][128], rq[4][128];
  int tid = threadIdx.x;
  int b = blockIdx.x;
  for (int i=tid;i<FIN*800;i+=512) (&xs[0][0])[i] = x[(size_t)b*(FIN*T_) + i];
  for (int i=tid;i<NF*FIN*KW;i+=512) wl[i]=cw[i];
  __syncthreads();
  int c = tid & 127, li = tid >> 7;
  float wr[FIN*KW];
  #pragma unroll
  for (int i=0;i<FIN*KW;i++) wr[i]=wl[c*FIN*KW+i];
  float cbv = cb[c];
  float s=0.f, q=0.f;
  for (int l=li; l<LOUT; l+=4){
    float a0=0.f, a1=0.f;
    #pragma unroll
    for (int f=0;f<FIN;f++){
      const float2* xp = (const float2*)&xs[f][0] + l;
      float xv[16];
      #pragma unroll
      for (int p=0;p<8;p++){ float2 v=xp[p]; xv[2*p]=v.x; xv[2*p+1]=v.y; }
      #pragma unroll
      for (int k=0;k<KW;k++){ float w=wr[f*KW+k]; a0 += w*xv[k]; a1 += w*xv[k+1]; }
    }
    float v = fmaxf(fmaxf(a0,a1)+cbv, 0.f);
    y16[((size_t)b*LOUT + l)*NF + c] = (_Float16)v;
    s += v; q += v*v;
  }
  rs[li][c]=s; rq[li][c]=q;
  __syncthreads();
  if (tid < 128){
    float ts = rs[0][c]+rs[1][c]+rs[2][c]+rs[3][c];
    float tq = rq[0][c]+rq[1][c]+rq[2][c]+rq[3][c];
    atomicAdd(&st[c], ts);
    atomicAdd(&st[128+c], tq);
  }
}

// -------- bias fold (gate-interleaved output order) --------
__global__ void k_prep_bias(const float* __restrict__ st,
    const float* __restrict__ g1, const float* __restrict__ b1v,
    const float* __restrict__ wf, const float* __restrict__ wb,
    const float* __restrict__ bif, const float* __restrict__ bhf,
    const float* __restrict__ bib, const float* __restrict__ bhb,
    float* __restrict__ bef, float* __restrict__ beb){
  int id = blockIdx.x*256 + threadIdx.x;
  if (id >= 2*NPAD) return;
  int dir = id/NPAD, g = id%NPAD;
  float* be = dir? beb : bef;
  if (g >= G4){ be[g]=0.f; return; }
  int src = (g&3)*HID + (g>>2);          // interleave: col 4u+gate <- row gate*150+u
  const float* wih = dir? wb : wf;
  float bias = dir? (bib[src]+bhb[src]) : (bif[src]+bhf[src]);
  const float Ninv = 1.f/((float)B_*(float)LOUT);
  for (int f=0;f<NF;f++){
    float m = st[f]*Ninv;
    float var = st[NF+f]*Ninv - m*m;
    float a = g1[f]*rsqrtf(var+EPS);
    float d = b1v[f] - m*a;
    bias += d*wih[(size_t)src*NF+f];
  }
  be[g] = bias;
}

// -------- pack AdaBN-folded w_ih into f16 MFMA fragments (interleaved cols) --------
__global__ void k_prep_wih(const float* __restrict__ st,
    const float* __restrict__ g1,
    const float* __restrict__ wf, const float* __restrict__ wb,
    _Float16* __restrict__ wT16){
  int id = blockIdx.x*256 + threadIdx.x;
  if (id >= 2*PNT*PKT*64) return;
  int lane = id & 63;
  int kt = (id>>6) & 3;
  int nt = (id>>8) % PNT;
  int dir = id / (PNT*PKT*64);
  const float* wih = dir? wb : wf;
  int n = nt*16 + (lane&15);
  int src = (n&3)*HID + (n>>2);
  int kb = kt*32 + (lane>>4)*8;
  const float Ninv = 1.f/((float)B_*(float)LOUT);
  half8 v;
  #pragma unroll
  for (int j=0;j<8;j++){
    int k = kb+j;
    float m = st[k]*Ninv;
    float var = st[NF+k]*Ninv - m*m;
    float a = g1[k]*rsqrtf(var+EPS);
    float f = (n < G4) ? wih[(size_t)src*NF + k]*a : 0.f;
    v[j] = (_Float16)f;
  }
  *(half8*)&wT16[(size_t)id*8] = v;
}

// -------- pack w_hh into f16 MFMA fragments (interleaved cols) --------
__global__ void k_prep_whh(const float* __restrict__ whf, const float* __restrict__ whb,
                           _Float16* __restrict__ wfrag){
  int id = blockIdx.x*256 + threadIdx.x;
  if (id >= 2*NT_*KT_*64) return;
  int lane = id & 63;
  int rest = id >> 6;
  int kt = rest % KT_;
  int nt = (rest/KT_) % NT_;
  int dir = rest / (KT_*NT_);
  const float* wh = dir? whb : whf;
  int n = nt*16 + (lane&15);
  int src = (n&3)*HID + (n>>2);
  int kb = kt*32 + (lane>>4)*8;
  half8 v;
  #pragma unroll
  for (int j=0;j<8;j++){
    int k = kb + j;
    float f = (n < G4 && k < HID) ? wh[(size_t)src*HID + k] : 0.f;
    v[j] = (_Float16)f;
  }
  *(half8*)&wfrag[(size_t)id*8] = v;
}

// ---------------- projection via f16 MFMA (unchanged — permutation-transparent) ----------------
__global__ __launch_bounds__(256) void k_proj2(const _Float16* __restrict__ y16,
    const _Float16* __restrict__ wT16,
    const float* __restrict__ bef, const float* __restrict__ beb,
    _Float16* __restrict__ pre16f, _Float16* __restrict__ pre16b,
    int t0f, int tc){
  __shared__ _Float16 Ds[128*136];
  __shared__ float bs[128];
  int dir = blockIdx.z;
  const _Float16* wfp = wT16 + (size_t)dir*PNT*PKT*64*8;
  const float* be = dir? beb : bef;
  _Float16* pre = dir? pre16b : pre16f;
  int tid = threadIdx.x, lane = tid&63, w = tid>>6;
  int trel = blockIdx.x>>2, bb = (blockIdx.x&3)*128;
  int t = dir ? (LOUT-1-t0f-trel) : (t0f+trel);
  int n0 = blockIdx.y*128;
  if (tid < 32) *(float4*)&bs[tid*4] = *(const float4*)&be[n0 + tid*4];

  f32x4 acc[2][8];
  #pragma unroll
  for (int i=0;i<2;i++)
    #pragma unroll
    for (int j=0;j<8;j++) acc[i][j] = (f32x4){0,0,0,0};

  int arow = lane&15, aq = (lane>>4)*8;
  const _Float16* a0p = y16 + ((size_t)(bb + (2*w)*16 + arow)*LOUT + t)*NF + aq;
  const _Float16* a1p = a0p + (size_t)16*LOUT*NF;
  int nb = n0 >> 4;
  #pragma unroll
  for (int kt=0; kt<PKT; kt++){
    half8 a0 = *(const half8*)(a0p + kt*32);
    half8 a1 = *(const half8*)(a1p + kt*32);
    #pragma unroll
    for (int nt=0; nt<8; nt++){
      half8 bf = *(const half8*)&wfp[(size_t)(((nb+nt)*PKT + kt)*64 + lane)*8];
      acc[0][nt] = __builtin_amdgcn_mfma_f32_16x16x32_f16(a0, bf, acc[0][nt], 0,0,0);
      acc[1][nt] = __builtin_amdgcn_mfma_f32_16x16x32_f16(a1, bf, acc[1][nt], 0,0,0);
    }
  }
  __syncthreads();
  int dcol = lane&15, dq = (lane>>4)*4;
  #pragma unroll
  for (int mi=0; mi<2; mi++){
    int rowb = (2*w+mi)*16 + dq;
    #pragma unroll
    for (int nt=0; nt<8; nt++){
      int colL = nt*16 + dcol;
      float bv = bs[colL];
      #pragma unroll
      for (int r=0;r<4;r++)
        Ds[(rowb+r)*136 + colL] = (_Float16)(acc[mi][nt][r] + bv);
    }
  }
  __syncthreads();
  int row = tid>>1, h = tid&1;
  const _Float16* src = &Ds[row*136 + h*64];
  _Float16* dst = pre + ((size_t)(trel*B_ + bb + row))*NPAD + n0 + h*64;
  #pragma unroll
  for (int qq=0; qq<8; qq++)
    *(float4*)(dst + qq*8) = *(const float4*)(src + qq*8);
}

// ---------------- recurrence v5b: swapped-operand MFMA, lane-local cell, padded pls ----------------
__global__ __launch_bounds__(1024)
void k_rec5(const _Float16* __restrict__ wfrag,
            const _Float16* __restrict__ pref, const _Float16* __restrict__ preb,
            float* __restrict__ hst, float* __restrict__ cst, float* __restrict__ mst,
            float* __restrict__ pooled, int tc, int first, int last){
  int dir = blockIdx.x >> 5;
  int b0 = (blockIdx.x & 31) * 16;
  const _Float16* pre = dir? preb : pref;
  int tid = threadIdx.x;
  int lane = tid & 63, w = tid >> 6;

  __shared__ __align__(16) _Float16 hh[2][16][168];    // 10752 B (stride 336B -> 2-way, free)
  __shared__ __align__(16) _Float16 pls[2][16][PSTR];  // 41472 B (stride 1296B -> 2-way, free)

  // ---- weight fragments (A-operand): waves 0-5: 3 nt, 6-15: 2 nt ----
  int cnt  = (w<6) ? 3 : 2;
  int base = (w<6) ? 3*w : 18 + 2*(w-6);
  const _Float16* wf = wfrag + (size_t)dir*NT_*KT_*64*8;
  half8 bfr[3][5];
  #pragma unroll
  for (int i=0;i<3;i++){
    #pragma unroll
    for (int kt=0;kt<KT_;kt++){
      int ntc = (i<cnt)? (base+i) : base;
      bfr[i][kt] = *(const half8*)&wf[(size_t)((ntc*KT_+kt)*64 + lane)*8];
    }
  }

  // ---- lane-local cell ownership ----
  int batch = lane & 15;
  int uo[3]; bool uv[3];
  #pragma unroll
  for (int i=0;i<3;i++){
    uo[i] = (base+i)*4 + (lane>>4);
    uv[i] = (i<cnt) && (uo[i] < HID);
  }

  // ---- staging mapping: 1280 half8 chunks = 16 rows x 80 chunks ----
  int srow0 = tid/80,        scol0 = (tid%80)*8;
  int srow1 = (tid+1024)/80, scol1 = ((tid+1024)%80)*8;
  bool s2 = tid < 256;

  // ---- init ----
  for (int i=tid; i<2*16*168; i+=1024) (&hh[0][0][0])[i] = (_Float16)0.f;
  float c[3], m[3], hl[3];
  #pragma unroll
  for (int i=0;i<3;i++){ c[i]=0.f; m[i]=-1e30f; hl[i]=0.f; }
  __syncthreads();
  if (!first){
    #pragma unroll
    for (int i=0;i<3;i++){
      if (uv[i]){
        size_t gi = ((size_t)(dir*B_ + b0 + batch))*HSTR + uo[i];
        c[i]=cst[gi]; m[i]=mst[gi]; hl[i]=hst[gi];
        hh[0][batch][uo[i]] = (_Float16)hl[i];
      }
    }
  }
  {
    half8 s0 = *(const half8*)(pre + ((size_t)(b0 + srow0))*NPAD + scol0);
    *(half8*)&pls[0][srow0][scol0] = s0;
    if (s2){
      half8 s1 = *(const half8*)(pre + ((size_t)(b0 + srow1))*NPAD + scol1);
      *(half8*)&pls[0][srow1][scol1] = s1;
    }
  }
  __syncthreads();

  int cur = 0;
  for (int t=0; t<tc; t++){
    int nxt = cur ^ 1;
    // 1. prefetch pre[t+1] -> regs
    half8 s0, s1;
    bool ld = (t+1 < tc);
    if (ld){
      size_t rbase = (size_t)(t+1)*B_ + b0;
      s0 = *(const half8*)(pre + (rbase + srow0)*NPAD + scol0);
      if (s2) s1 = *(const half8*)(pre + (rbase + srow1)*NPAD + scol1);
    }
    // 2. MFMA: D[gate_col][batch] = W x H^T
    f32x4 acc0={0,0,0,0}, acc1={0,0,0,0}, acc2={0,0,0,0};
    #pragma unroll
    for (int kt=0; kt<KT_; kt++){
      half8 a = *(const half8*)&hh[cur][batch][kt*32 + (lane>>4)*8];
      acc0 = __builtin_amdgcn_mfma_f32_16x16x32_f16(bfr[0][kt], a, acc0, 0,0,0);
      acc1 = __builtin_amdgcn_mfma_f32_16x16x32_f16(bfr[1][kt], a, acc1, 0,0,0);
      if (cnt>2) acc2 = __builtin_amdgcn_mfma_f32_16x16x32_f16(bfr[2][kt], a, acc2, 0,0,0);
    }
    // 3. cell: lane-local
    #define CELL(ACC, I)                                                     \
    if (uv[I]){                                                              \
      half4 pv = *(const half4*)&pls[cur][batch][4*uo[I]];                   \
      float xi = ACC[0] + (float)pv[0];                                      \
      float xf = ACC[1] + (float)pv[1];                                      \
      float xg = ACC[2] + (float)pv[2];                                      \
      float xo = ACC[3] + (float)pv[3];                                      \
      float ig=hsig(xi), fg=hsig(xf), og=hsig(xo), gg=ftanh(xg);             \
      c[I] = fg*c[I] + ig*gg;                                                \
      float hv = og*ftanh(c[I]);                                             \
      m[I] = fmaxf(m[I], hv);                                                \
      hl[I] = hv;                                                            \
      hh[nxt][batch][uo[I]] = (_Float16)hv;                                  \
    }
    CELL(acc0, 0)
    CELL(acc1, 1)
    CELL(acc2, 2)
    #undef CELL
    // 4. write prefetched pre -> pls[nxt]
    if (ld){
      *(half8*)&pls[nxt][srow0][scol0] = s0;
      if (s2) *(half8*)&pls[nxt][srow1][scol1] = s1;
    }
    __syncthreads();
    cur = nxt;
  }

  #pragma unroll
  for (int i=0;i<3;i++){
    if (uv[i]){
      size_t gi = ((size_t)(dir*B_ + b0 + batch))*HSTR + uo[i];
      cst[gi]=c[i]; mst[gi]=m[i]; hst[gi]=hl[i];
      if (last) pooled[(size_t)(b0+batch)*300 + dir*HID + uo[i]] = m[i];
    }
  }
}

// ---------------- tails ----------------
__global__ void k_stats2(const float* __restrict__ pooled,
    const float* __restrict__ g2, const float* __restrict__ b2,
    float* __restrict__ a2, float* __restrict__ d2){
  int f = threadIdx.x;
  if (f >= 300) return;
  float s=0.f,q=0.f;
  for (int b=0;b<B_;b++){ float v = pooled[(size_t)b*300+f]; s+=v; q+=v*v; }
  float m = s*(1.f/B_), var = q*(1.f/B_) - m*m;
  float a = g2[f]*rsqrtf(var+EPS);
  a2[f]=a; d2[f]=b2[f]-m*a;
}

__global__ void k_fc1(const float* __restrict__ pooled,
    const float* __restrict__ a2, const float* __restrict__ d2,
    const float* __restrict__ w1, const float* __restrict__ fb1,
    float* __restrict__ z1){
  int o = blockIdx.x*256 + threadIdx.x;
  if (o >= B_*50) return;
  int b = o/50, j = o%50;
  float acc = fb1[j];
  for (int f=0;f<300;f++)
    acc += (a2[f]*pooled[(size_t)b*300+f] + d2[f]) * w1[j*300+f];
  z1[o] = fmaxf(acc,0.f);
}

__global__ void k_stats3(const float* __restrict__ z1,
    const float* __restrict__ g3, const float* __restrict__ b3,
    float* __restrict__ a3, float* __restrict__ d3){
  int f = threadIdx.x;
  if (f >= 50) return;
  float s=0.f,q=0.f;
  for (int b=0;b<B_;b++){ float v = z1[(size_t)b*50+f]; s+=v; q+=v*v; }
  float m = s*(1.f/B_), var = q*(1.f/B_) - m*m;
  float a = g3[f]*rsqrtf(var+EPS);
  a3[f]=a; d3[f]=b3[f]-m*a;
}

__global__ void k_fc2(const float* __restrict__ z1,
    const float* __restrict__ a3, const float* __restrict__ d3,
    const float* __restrict__ w2, const float* __restrict__ fb2,
    float* __restrict__ out){
  int b = blockIdx.x;
  int t = threadIdx.x;
  __shared__ float zl[50];
  __shared__ float lg[10];
  if (t<50) zl[t] = a3[t]*z1[(size_t)b*50+t] + d3[t];
  __syncthreads();
  if (t<10){
    float acc = fb2[t];
    for (int j=0;j<50;j++) acc += zl[j]*w2[t*50+j];
    lg[t]=acc;
  }
  __syncthreads();
  if (t<10){
    float m = lg[0];
    #pragma unroll
    for (int i=1;i<10;i++) m = fmaxf(m,lg[i]);
    float s = 0.f;
    #pragma unroll
    for (int i=0;i<10;i++) s += expf(lg[i]-m);
    out[(size_t)b*10+t] = expf(lg[t]-m)/s;
  }
}

extern "C" void kernel_launch(void* const* d_in, const int* in_sizes, int n_in,
                              void* d_out, int out_size, void* d_ws, size_t ws_size,
                              hipStream_t stream) {
  const float* x    = (const float*)d_in[0];
  const float* cw   = (const float*)d_in[1];
  const float* cb   = (const float*)d_in[2];
  const float* g1   = (const float*)d_in[3];
  const float* b1v  = (const float*)d_in[4];
  const float* wihf = (const float*)d_in[5];
  const float* whhf = (const float*)d_in[6];
  const float* bihf = (const float*)d_in[7];
  const float* bhhf = (const float*)d_in[8];
  const float* wihb = (const float*)d_in[9];
  const float* whhb = (const float*)d_in[10];
  const float* bihb = (const float*)d_in[11];
  const float* bhhb = (const float*)d_in[12];
  const float* g2   = (const float*)d_in[13];
  const float* b2   = (const float*)d_in[14];
  const float* w1   = (const float*)d_in[15];
  const float* fb1  = (const float*)d_in[16];
  const float* g3   = (const float*)d_in[17];
  const float* b3   = (const float*)d_in[18];
  const float* w2   = (const float*)d_in[19];
  const float* fb2  = (const float*)d_in[20];
  float* out = (float*)d_out;

  uint8_t* base = (uint8_t*)d_ws;
  size_t off = 0;
  auto allocB = [&](size_t nbytes)->uint8_t*{
    uint8_t* p = base + off;
    off = (off + nbytes + 255) & ~(size_t)255;
    return p;
  };
  _Float16* y16   = (_Float16*)allocB((size_t)B_*LOUT*NF*2);
  float* st       = (float*)allocB(256*4);
  _Float16* wT16  = (_Float16*)allocB((size_t)2*PNT*PKT*64*8*2);
  float* bef      = (float*)allocB(NPAD*4);
  float* beb      = (float*)allocB(NPAD*4);
  _Float16* wfrag = (_Float16*)allocB((size_t)2*NT_*KT_*64*8*2);
  float* hst      = (float*)allocB((size_t)2*B_*HSTR*4);
  float* cst      = (float*)allocB((size_t)2*B_*HSTR*4);
  float* mst      = (float*)allocB((size_t)2*B_*HSTR*4);
  float* pooled   = (float*)allocB((size_t)B_*300*4);
  float* a2       = (float*)allocB(320*4);
  float* d2       = (float*)allocB(320*4);
  float* z1       = (float*)allocB((size_t)B_*50*4);
  float* a3       = (float*)allocB(64*4);
  float* d3       = (float*)allocB(64*4);
  size_t fixedEnd = off;

  size_t per_t = (size_t)2*B_*NPAD*2;   // both dirs, f16
  size_t avail = (ws_size > fixedEnd + 4096) ? (ws_size - fixedEnd - 4096) : 0;
  int tcmax = (int)(avail / per_t);
  if (tcmax < 1) tcmax = 1;
  if (tcmax > LOUT) tcmax = LOUT;
  int nch = (LOUT + tcmax - 1) / tcmax;
  int TC = (LOUT + nch - 1) / nch;
  _Float16* pre16f = (_Float16*)allocB((size_t)TC*B_*NPAD*2);
  _Float16* pre16b = (_Float16*)allocB((size_t)TC*B_*NPAD*2);

  hipMemsetAsync(st, 0, 256*4, stream);
  k_conv2<<<B_, 512, 0, stream>>>(x, cw, cb, y16, st);
  k_prep_bias<<<(2*NPAD+255)/256, 256, 0, stream>>>(st, g1, b1v, wihf, wihb,
                                                    bihf, bhhf, bihb, bhhb, bef, beb);
  k_prep_wih<<<(2*PNT*PKT*64+255)/256, 256, 0, stream>>>(st, g1, wihf, wihb, wT16);
  k_prep_whh<<<(2*NT_*KT_*64+255)/256, 256, 0, stream>>>(whhf, whhb, wfrag);

  int t0 = 0; int first = 1;
  while (t0 < LOUT){
    int tc = (TC < LOUT - t0) ? TC : (LOUT - t0);
    int lastc = (t0 + tc >= LOUT) ? 1 : 0;
    k_proj2<<<dim3(tc*4, 5, 2), 256, 0, stream>>>(y16, wT16, bef, beb,
                                                  pre16f, pre16b, t0, tc);
    k_rec5<<<64, 1024, 0, stream>>>(wfrag, pre16f, pre16b,
                                    hst, cst, mst, pooled, tc, first, lastc);
    t0 += tc; first = 0;
  }
  k_stats2<<<1, 320, 0, stream>>>(pooled, g2, b2, a2, d2);
  k_fc1<<<(B_*50+255)/256, 256, 0, stream>>>(pooled, a2, d2, w1, fb1, z1);
  k_stats3<<<1, 64, 0, stream>>>(z1, g3, b3, a3, d3);
  k_fc2<<<B_, 64, 0, stream>>>(z1, a3, d3, w2, fb2, out);
}

// Round 12
// 895.133 us; speedup vs baseline: 2.3217x; 1.2331x over previous
//
#include <hip/hip_runtime.h>
#include <math.h>

#define B_   512
#define T_   800
#define FIN  3
#define NF   128
#define KW   15
#define HID  150
#define LOUT 393
#define G4   600
#define NPAD 640
#define EPS  1e-5f

#define NT_  38          // whh N tiles of 16 over 608 (interleaved gate order)
#define KT_  5           // whh K tiles of 32 over 160
#define HSTR 152
#define PNT  40          // wih N tiles of 16 over 640
#define PKT  4           // wih K tiles of 32 over 128
#define PSTR 648         // pls row stride: 1296B -> 2-way bank alias (free)

typedef _Float16 half8 __attribute__((ext_vector_type(8)));
typedef _Float16 half4 __attribute__((ext_vector_type(4)));
typedef float f32x4 __attribute__((ext_vector_type(4)));

__device__ __forceinline__ float hsig(float x){ return fminf(fmaxf(0.2f*x+0.5f,0.f),1.f); }
__device__ __forceinline__ float ftanh(float x){ float e=__expf(2.f*x); return 1.f - 2.f/(e+1.f); }

// ------- conv + relu + maxpool2 + f16 store + AdaBN1 stats (fused) -------
__global__ __launch_bounds__(512) void k_conv2(const float* __restrict__ x,
        const float* __restrict__ cw, const float* __restrict__ cb,
        _Float16* __restrict__ y16, float* __restrict__ st){
  __shared__ float xs[FIN][800];
  __shared__ float wl[NF*FIN*KW];
  __shared__ float rs[4][128], rq[4][128];
  int tid = threadIdx.x;
  int b = blockIdx.x;
  for (int i=tid;i<FIN*800;i+=512) (&xs[0][0])[i] = x[(size_t)b*(FIN*T_) + i];
  for (int i=tid;i<NF*FIN*KW;i+=512) wl[i]=cw[i];
  __syncthreads();
  int c = tid & 127, li = tid >> 7;
  float wr[FIN*KW];
  #pragma unroll
  for (int i=0;i<FIN*KW;i++) wr[i]=wl[c*FIN*KW+i];
  float cbv = cb[c];
  float s=0.f, q=0.f;
  for (int l=li; l<LOUT; l+=4){
    float a0=0.f, a1=0.f;
    #pragma unroll
    for (int f=0;f<FIN;f++){
      const float2* xp = (const float2*)&xs[f][0] + l;
      float xv[16];
      #pragma unroll
      for (int p=0;p<8;p++){ float2 v=xp[p]; xv[2*p]=v.x; xv[2*p+1]=v.y; }
      #pragma unroll
      for (int k=0;k<KW;k++){ float w=wr[f*KW+k]; a0 += w*xv[k]; a1 += w*xv[k+1]; }
    }
    float v = fmaxf(fmaxf(a0,a1)+cbv, 0.f);
    y16[((size_t)b*LOUT + l)*NF + c] = (_Float16)v;
    s += v; q += v*v;
  }
  rs[li][c]=s; rq[li][c]=q;
  __syncthreads();
  if (tid < 128){
    float ts = rs[0][c]+rs[1][c]+rs[2][c]+rs[3][c];
    float tq = rq[0][c]+rq[1][c]+rq[2][c]+rq[3][c];
    atomicAdd(&st[c], ts);
    atomicAdd(&st[128+c], tq);
  }
}

// -------- bias fold (gate-interleaved output order) --------
__global__ void k_prep_bias(const float* __restrict__ st,
    const float* __restrict__ g1, const float* __restrict__ b1v,
    const float* __restrict__ wf, const float* __restrict__ wb,
    const float* __restrict__ bif, const float* __restrict__ bhf,
    const float* __restrict__ bib, const float* __restrict__ bhb,
    float* __restrict__ bef, float* __restrict__ beb){
  int id = blockIdx.x*256 + threadIdx.x;
  if (id >= 2*NPAD) return;
  int dir = id/NPAD, g = id%NPAD;
  float* be = dir? beb : bef;
  if (g >= G4){ be[g]=0.f; return; }
  int src = (g&3)*HID + (g>>2);          // interleave: col 4u+gate <- row gate*150+u
  const float* wih = dir? wb : wf;
  float bias = dir? (bib[src]+bhb[src]) : (bif[src]+bhf[src]);
  const float Ninv = 1.f/((float)B_*(float)LOUT);
  for (int f=0;f<NF;f++){
    float m = st[f]*Ninv;
    float var = st[NF+f]*Ninv - m*m;
    float a = g1[f]*rsqrtf(var+EPS);
    float d = b1v[f] - m*a;
    bias += d*wih[(size_t)src*NF+f];
  }
  be[g] = bias;
}

// -------- pack AdaBN-folded w_ih into f16 MFMA fragments (interleaved cols) --------
__global__ void k_prep_wih(const float* __restrict__ st,
    const float* __restrict__ g1,
    const float* __restrict__ wf, const float* __restrict__ wb,
    _Float16* __restrict__ wT16){
  int id = blockIdx.x*256 + threadIdx.x;
  if (id >= 2*PNT*PKT*64) return;
  int lane = id & 63;
  int kt = (id>>6) & 3;
  int nt = (id>>8) % PNT;
  int dir = id / (PNT*PKT*64);
  const float* wih = dir? wb : wf;
  int n = nt*16 + (lane&15);
  int src = (n&3)*HID + (n>>2);
  int kb = kt*32 + (lane>>4)*8;
  const float Ninv = 1.f/((float)B_*(float)LOUT);
  half8 v;
  #pragma unroll
  for (int j=0;j<8;j++){
    int k = kb+j;
    float m = st[k]*Ninv;
    float var = st[NF+k]*Ninv - m*m;
    float a = g1[k]*rsqrtf(var+EPS);
    float f = (n < G4) ? wih[(size_t)src*NF + k]*a : 0.f;
    v[j] = (_Float16)f;
  }
  *(half8*)&wT16[(size_t)id*8] = v;
}

// -------- pack w_hh into f16 MFMA fragments (interleaved cols) --------
__global__ void k_prep_whh(const float* __restrict__ whf, const float* __restrict__ whb,
                           _Float16* __restrict__ wfrag){
  int id = blockIdx.x*256 + threadIdx.x;
  if (id >= 2*NT_*KT_*64) return;
  int lane = id & 63;
  int rest = id >> 6;
  int kt = rest % KT_;
  int nt = (rest/KT_) % NT_;
  int dir = rest / (KT_*NT_);
  const float* wh = dir? whb : whf;
  int n = nt*16 + (lane&15);
  int src = (n&3)*HID + (n>>2);
  int kb = kt*32 + (lane>>4)*8;
  half8 v;
  #pragma unroll
  for (int j=0;j<8;j++){
    int k = kb + j;
    float f = (n < G4 && k < HID) ? wh[(size_t)src*HID + k] : 0.f;
    v[j] = (_Float16)f;
  }
  *(half8*)&wfrag[(size_t)id*8] = v;
}

// ================= mega kernel: rec (blocks < nrec) + proj next chunk =================
// rec path: 16 waves, rec5 core verbatim.
// proj path: 16 waves x 1 m-subtile x 8 ntiles, acc[8] (32 VGPR), NO LDS,
//            direct f16 global stores with bias from L2.
__global__ __launch_bounds__(1024)
void k_mega(const _Float16* __restrict__ wfrag,
            const _Float16* __restrict__ wT16,
            const float* __restrict__ bef, const float* __restrict__ beb,
            const _Float16* __restrict__ y16,
            const _Float16* __restrict__ prf, const _Float16* __restrict__ prb,
            _Float16* __restrict__ pwf, _Float16* __restrict__ pwb,
            float* __restrict__ hst, float* __restrict__ cst, float* __restrict__ mst,
            float* __restrict__ pooled,
            int nrec, int tc, int first, int last, int t0p){
  __shared__ __align__(16) _Float16 hh[2][16][168];    // rec only
  __shared__ __align__(16) _Float16 pls[2][16][PSTR];  // rec only
  int tid = threadIdx.x;
  int bid = blockIdx.x;

  if (bid < nrec){
    // ---------------- rec path (rec5 core) ----------------
    int dir = bid >> 5;
    int b0 = (bid & 31) * 16;
    const _Float16* pre = dir? prb : prf;
    int lane = tid & 63, w = tid >> 6;

    int cnt  = (w<6) ? 3 : 2;
    int base = (w<6) ? 3*w : 18 + 2*(w-6);
    const _Float16* wf = wfrag + (size_t)dir*NT_*KT_*64*8;
    half8 bfr[3][5];
    #pragma unroll
    for (int i=0;i<3;i++){
      #pragma unroll
      for (int kt=0;kt<KT_;kt++){
        int ntc = (i<cnt)? (base+i) : base;
        bfr[i][kt] = *(const half8*)&wf[(size_t)((ntc*KT_+kt)*64 + lane)*8];
      }
    }

    int batch = lane & 15;
    int uo[3]; bool uv[3];
    #pragma unroll
    for (int i=0;i<3;i++){
      uo[i] = (base+i)*4 + (lane>>4);
      uv[i] = (i<cnt) && (uo[i] < HID);
    }

    int srow0 = tid/80,        scol0 = (tid%80)*8;
    int srow1 = (tid+1024)/80, scol1 = ((tid+1024)%80)*8;
    bool s2 = tid < 256;

    for (int i=tid; i<2*16*168; i+=1024) (&hh[0][0][0])[i] = (_Float16)0.f;
    float c[3], m[3], hl[3];
    #pragma unroll
    for (int i=0;i<3;i++){ c[i]=0.f; m[i]=-1e30f; hl[i]=0.f; }
    __syncthreads();
    if (!first){
      #pragma unroll
      for (int i=0;i<3;i++){
        if (uv[i]){
          size_t gi = ((size_t)(dir*B_ + b0 + batch))*HSTR + uo[i];
          c[i]=cst[gi]; m[i]=mst[gi]; hl[i]=hst[gi];
          hh[0][batch][uo[i]] = (_Float16)hl[i];
        }
      }
    }
    {
      half8 s0 = *(const half8*)(pre + ((size_t)(b0 + srow0))*NPAD + scol0);
      *(half8*)&pls[0][srow0][scol0] = s0;
      if (s2){
        half8 s1 = *(const half8*)(pre + ((size_t)(b0 + srow1))*NPAD + scol1);
        *(half8*)&pls[0][srow1][scol1] = s1;
      }
    }
    __syncthreads();

    int cur = 0;
    for (int t=0; t<tc; t++){
      int nxt = cur ^ 1;
      half8 s0, s1;
      bool ld = (t+1 < tc);
      if (ld){
        size_t rbase = (size_t)(t+1)*B_ + b0;
        s0 = *(const half8*)(pre + (rbase + srow0)*NPAD + scol0);
        if (s2) s1 = *(const half8*)(pre + (rbase + srow1)*NPAD + scol1);
      }
      f32x4 acc0={0,0,0,0}, acc1={0,0,0,0}, acc2={0,0,0,0};
      #pragma unroll
      for (int kt=0; kt<KT_; kt++){
        half8 a = *(const half8*)&hh[cur][batch][kt*32 + (lane>>4)*8];
        acc0 = __builtin_amdgcn_mfma_f32_16x16x32_f16(bfr[0][kt], a, acc0, 0,0,0);
        acc1 = __builtin_amdgcn_mfma_f32_16x16x32_f16(bfr[1][kt], a, acc1, 0,0,0);
        if (cnt>2) acc2 = __builtin_amdgcn_mfma_f32_16x16x32_f16(bfr[2][kt], a, acc2, 0,0,0);
      }
      #define CELL(ACC, I)                                                     \
      if (uv[I]){                                                              \
        half4 pv = *(const half4*)&pls[cur][batch][4*uo[I]];                   \
        float xi = ACC[0] + (float)pv[0];                                      \
        float xf = ACC[1] + (float)pv[1];                                      \
        float xg = ACC[2] + (float)pv[2];                                      \
        float xo = ACC[3] + (float)pv[3];                                      \
        float ig=hsig(xi), fg=hsig(xf), og=hsig(xo), gg=ftanh(xg);             \
        c[I] = fg*c[I] + ig*gg;                                                \
        float hv = og*ftanh(c[I]);                                             \
        m[I] = fmaxf(m[I], hv);                                                \
        hl[I] = hv;                                                            \
        hh[nxt][batch][uo[I]] = (_Float16)hv;                                  \
      }
      CELL(acc0, 0)
      CELL(acc1, 1)
      CELL(acc2, 2)
      #undef CELL
      if (ld){
        *(half8*)&pls[nxt][srow0][scol0] = s0;
        if (s2) *(half8*)&pls[nxt][srow1][scol1] = s1;
      }
      __syncthreads();
      cur = nxt;
    }

    #pragma unroll
    for (int i=0;i<3;i++){
      if (uv[i]){
        size_t gi = ((size_t)(dir*B_ + b0 + batch))*HSTR + uo[i];
        cst[gi]=c[i]; mst[gi]=m[i]; hst[gi]=hl[i];
        if (last) pooled[(size_t)(b0+batch)*300 + dir*HID + uo[i]] = m[i];
      }
    }
    return;
  }

  // ---------------- proj path: pre[t0p..] for next chunk ----------------
  {
    int pb = bid - nrec;
    int dir  = pb & 1;
    int t5   = pb >> 1;
    int by   = t5 % 5;
    int t2   = t5 / 5;
    int mb   = t2 & 1;
    int trel = t2 >> 1;
    const _Float16* wfp = wT16 + (size_t)dir*PNT*PKT*64*8;
    const float* be = dir? beb : bef;
    _Float16* pre = dir? pwb : pwf;
    int t = dir ? (LOUT-1-t0p-trel) : (t0p+trel);
    int n0 = by*128, nb = n0>>4;
    int lane = tid & 63, ww = tid >> 6;
    int m0 = mb*256 + ww*16;
    int arow = lane&15, aq = (lane>>4)*8;
    const _Float16* ap = y16 + ((size_t)(m0+arow)*LOUT + t)*NF + aq;
    f32x4 acc[8];
    #pragma unroll
    for (int j=0;j<8;j++) acc[j] = (f32x4){0,0,0,0};
    #pragma unroll
    for (int kt=0; kt<PKT; kt++){
      half8 a = *(const half8*)(ap + kt*32);
      #pragma unroll
      for (int nt=0; nt<8; nt++){
        half8 bf = *(const half8*)&wfp[(size_t)(((nb+nt)*PKT + kt)*64 + lane)*8];
        acc[nt] = __builtin_amdgcn_mfma_f32_16x16x32_f16(a, bf, acc[nt], 0,0,0);
      }
    }
    int dcol = lane&15, dq = (lane>>4)*4;
    size_t rowg = (size_t)trel*B_ + m0 + dq;
    #pragma unroll
    for (int nt=0; nt<8; nt++){
      int colL = n0 + nt*16 + dcol;
      float bv = be[colL];
      #pragma unroll
      for (int r=0;r<4;r++)
        pre[(rowg+r)*NPAD + colL] = (_Float16)(acc[nt][r] + bv);
    }
  }
}

// ---------------- tails ----------------
__global__ void k_stats2(const float* __restrict__ pooled,
    const float* __restrict__ g2, const float* __restrict__ b2,
    float* __restrict__ a2, float* __restrict__ d2){
  int f = threadIdx.x;
  if (f >= 300) return;
  float s=0.f,q=0.f;
  for (int b=0;b<B_;b++){ float v = pooled[(size_t)b*300+f]; s+=v; q+=v*v; }
  float m = s*(1.f/B_), var = q*(1.f/B_) - m*m;
  float a = g2[f]*rsqrtf(var+EPS);
  a2[f]=a; d2[f]=b2[f]-m*a;
}

__global__ void k_fc1(const float* __restrict__ pooled,
    const float* __restrict__ a2, const float* __restrict__ d2,
    const float* __restrict__ w1, const float* __restrict__ fb1,
    float* __restrict__ z1){
  int o = blockIdx.x*256 + threadIdx.x;
  if (o >= B_*50) return;
  int b = o/50, j = o%50;
  float acc = fb1[j];
  for (int f=0;f<300;f++)
    acc += (a2[f]*pooled[(size_t)b*300+f] + d2[f]) * w1[j*300+f];
  z1[o] = fmaxf(acc,0.f);
}

__global__ void k_stats3(const float* __restrict__ z1,
    const float* __restrict__ g3, const float* __restrict__ b3,
    float* __restrict__ a3, float* __restrict__ d3){
  int f = threadIdx.x;
  if (f >= 50) return;
  float s=0.f,q=0.f;
  for (int b=0;b<B_;b++){ float v = z1[(size_t)b*50+f]; s+=v; q+=v*v; }
  float m = s*(1.f/B_), var = q*(1.f/B_) - m*m;
  float a = g3[f]*rsqrtf(var+EPS);
  a3[f]=a; d3[f]=b3[f]-m*a;
}

__global__ void k_fc2(const float* __restrict__ z1,
    const float* __restrict__ a3, const float* __restrict__ d3,
    const float* __restrict__ w2, const float* __restrict__ fb2,
    float* __restrict__ out){
  int b = blockIdx.x;
  int t = threadIdx.x;
  __shared__ float zl[50];
  __shared__ float lg[10];
  if (t<50) zl[t] = a3[t]*z1[(size_t)b*50+t] + d3[t];
  __syncthreads();
  if (t<10){
    float acc = fb2[t];
    for (int j=0;j<50;j++) acc += zl[j]*w2[t*50+j];
    lg[t]=acc;
  }
  __syncthreads();
  if (t<10){
    float m = lg[0];
    #pragma unroll
    for (int i=1;i<10;i++) m = fmaxf(m,lg[i]);
    float s = 0.f;
    #pragma unroll
    for (int i=0;i<10;i++) s += expf(lg[i]-m);
    out[(size_t)b*10+t] = expf(lg[t]-m)/s;
  }
}

extern "C" void kernel_launch(void* const* d_in, const int* in_sizes, int n_in,
                              void* d_out, int out_size, void* d_ws, size_t ws_size,
                              hipStream_t stream) {
  const float* x    = (const float*)d_in[0];
  const float* cw   = (const float*)d_in[1];
  const float* cb   = (const float*)d_in[2];
  const float* g1   = (const float*)d_in[3];
  const float* b1v  = (const float*)d_in[4];
  const float* wihf = (const float*)d_in[5];
  const float* whhf = (const float*)d_in[6];
  const float* bihf = (const float*)d_in[7];
  const float* bhhf = (const float*)d_in[8];
  const float* wihb = (const float*)d_in[9];
  const float* whhb = (const float*)d_in[10];
  const float* bihb = (const float*)d_in[11];
  const float* bhhb = (const float*)d_in[12];
  const float* g2   = (const float*)d_in[13];
  const float* b2   = (const float*)d_in[14];
  const float* w1   = (const float*)d_in[15];
  const float* fb1  = (const float*)d_in[16];
  const float* g3   = (const float*)d_in[17];
  const float* b3   = (const float*)d_in[18];
  const float* w2   = (const float*)d_in[19];
  const float* fb2  = (const float*)d_in[20];
  float* out = (float*)d_out;

  uint8_t* base = (uint8_t*)d_ws;
  size_t off = 0;
  auto allocB = [&](size_t nbytes)->uint8_t*{
    uint8_t* p = base + off;
    off = (off + nbytes + 255) & ~(size_t)255;
    return p;
  };
  _Float16* y16   = (_Float16*)allocB((size_t)B_*LOUT*NF*2);
  float* st       = (float*)allocB(256*4);
  _Float16* wT16  = (_Float16*)allocB((size_t)2*PNT*PKT*64*8*2);
  float* bef      = (float*)allocB(NPAD*4);
  float* beb      = (float*)allocB(NPAD*4);
  _Float16* wfrag = (_Float16*)allocB((size_t)2*NT_*KT_*64*8*2);
  float* hst      = (float*)allocB((size_t)2*B_*HSTR*4);
  float* cst      = (float*)allocB((size_t)2*B_*HSTR*4);
  float* mst      = (float*)allocB((size_t)2*B_*HSTR*4);
  float* pooled   = (float*)allocB((size_t)B_*300*4);
  float* a2       = (float*)allocB(320*4);
  float* d2       = (float*)allocB(320*4);
  float* z1       = (float*)allocB((size_t)B_*50*4);
  float* a3       = (float*)allocB(64*4);
  float* d3       = (float*)allocB(64*4);
  size_t fixedEnd = off;

  size_t avail = (ws_size > fixedEnd + 4096) ? (ws_size - fixedEnd - 4096) : 0;
  size_t per_t1 = (size_t)2*B_*NPAD*2;   // single chunk (one buffer set)
  size_t per_t2 = (size_t)4*B_*NPAD*2;   // double-buffered sets
  int nch, TC;
  if (avail / per_t1 >= (size_t)LOUT){
    nch = 1; TC = LOUT;
  } else {
    int tcmax = (int)(avail / per_t2);
    if (tcmax < 1) tcmax = 1;
    if (tcmax > LOUT) tcmax = LOUT;
    nch = (LOUT + tcmax - 1) / tcmax;
    TC = (LOUT + nch - 1) / nch;
  }
  _Float16* preA_f = (_Float16*)allocB((size_t)TC*B_*NPAD*2);
  _Float16* preA_b = (_Float16*)allocB((size_t)TC*B_*NPAD*2);
  _Float16* preB_f = preA_f;
  _Float16* preB_b = preA_b;
  if (nch > 1){
    preB_f = (_Float16*)allocB((size_t)TC*B_*NPAD*2);
    preB_b = (_Float16*)allocB((size_t)TC*B_*NPAD*2);
  }
  auto t0of = [&](int k){ return k*TC; };
  auto tcof = [&](int k){ int r = LOUT - k*TC; return (r < TC) ? r : TC; };

  hipMemsetAsync(st, 0, 256*4, stream);
  k_conv2<<<B_, 512, 0, stream>>>(x, cw, cb, y16, st);
  k_prep_bias<<<(2*NPAD+255)/256, 256, 0, stream>>>(st, g1, b1v, wihf, wihb,
                                                    bihf, bhhf, bihb, bhhb, bef, beb);
  k_prep_wih<<<(2*PNT*PKT*64+255)/256, 256, 0, stream>>>(st, g1, wihf, wihb, wT16);
  k_prep_whh<<<(2*NT_*KT_*64+255)/256, 256, 0, stream>>>(whhf, whhb, wfrag);

  // launch 0: proj-only for chunk 0 -> set A
  k_mega<<<tcof(0)*20, 1024, 0, stream>>>(wfrag, wT16, bef, beb, y16,
      preA_f, preA_b, preA_f, preA_b, hst, cst, mst, pooled,
      0, 0, 0, 0, t0of(0));
  // chunk loop: rec(k) on set(k%2)  ||  proj(k+1) -> set((k+1)%2)
  for (int k=0; k<nch; k++){
    int hasN = (k+1 < nch) ? 1 : 0;
    _Float16* rf = (k & 1) ? preB_f : preA_f;
    _Float16* rb = (k & 1) ? preB_b : preA_b;
    _Float16* wf_ = ((k+1) & 1) ? preB_f : preA_f;
    _Float16* wb_ = ((k+1) & 1) ? preB_b : preA_b;
    int grid = 64 + (hasN ? tcof(k+1)*20 : 0);
    k_mega<<<grid, 1024, 0, stream>>>(wfrag, wT16, bef, beb, y16,
        rf, rb, wf_, wb_, hst, cst, mst, pooled,
        64, tcof(k), (k==0) ? 1 : 0, hasN ? 0 : 1, hasN ? t0of(k+1) : 0);
  }

  k_stats2<<<1, 320, 0, stream>>>(pooled, g2, b2, a2, d2);
  k_fc1<<<(B_*50+255)/256, 256, 0, stream>>>(pooled, a2, d2, w1, fb1, z1);
  k_stats3<<<1, 64, 0, stream>>>(z1, g3, b3, a3, d3);
  k_fc2<<<B_, 64, 0, stream>>>(z1, a3, d3, w2, fb2, out);
}

// Round 13
// 888.325 us; speedup vs baseline: 2.3395x; 1.0077x over previous
//
#include <hip/hip_runtime.h>
#include <math.h>

#define B_   512
#define T_   800
#define FIN  3
#define NF   128
#define KW   15
#define HID  150
#define LOUT 393
#define G4   600
#define NPAD 640
#define EPS  1e-5f

#define NT_  38          // whh N tiles of 16 over 608 (interleaved gate order)
#define KT_  5           // whh K tiles of 32 over 160
#define HSTR 152
#define PNT  40          // wih N tiles of 16 over 640
#define PKT  4           // wih K tiles of 32 over 128
#define PSTR 648         // pls row stride: 1296B -> 2-way bank alias (free)

typedef _Float16 half8 __attribute__((ext_vector_type(8)));
typedef _Float16 half4 __attribute__((ext_vector_type(4)));
typedef float f32x4 __attribute__((ext_vector_type(4)));

__device__ __forceinline__ float hsig(float x){ return fminf(fmaxf(0.2f*x+0.5f,0.f),1.f); }
__device__ __forceinline__ float ftanh(float x){ float e=__expf(2.f*x); return 1.f - 2.f/(e+1.f); }

// ------- conv3: conv + relu + maxpool2 + f16 store + AdaBN1 stats -------
// register-window: 6 float4 LDS reads per f per 4 outputs (vs 24 scalar pairs/output)
__global__ __launch_bounds__(512) void k_conv3(const float* __restrict__ x,
        const float* __restrict__ cw, const float* __restrict__ cb,
        _Float16* __restrict__ y16, float* __restrict__ st){
  __shared__ __align__(16) float xs[FIN][808];
  __shared__ float wl[NF*FIN*KW];
  __shared__ float rs[4][128], rq[4][128];
  int tid = threadIdx.x;
  int b = blockIdx.x;
  for (int i=tid;i<FIN*800;i+=512){ int f=i/800, p=i-f*800;
    xs[f][p] = x[(size_t)b*(FIN*T_) + i]; }
  if (tid < FIN*8){ int f=tid/8, p=800+(tid&7); xs[f][p]=0.f; }
  for (int i=tid;i<NF*FIN*KW;i+=512) wl[i]=cw[i];
  __syncthreads();
  int c = tid & 127, li = tid >> 7;
  float wr[FIN*KW];
  #pragma unroll
  for (int i=0;i<FIN*KW;i++) wr[i]=wl[c*FIN*KW+i];
  float cbv = cb[c];
  float s=0.f, q=0.f;
  int l0 = li*100;
  int lend = (l0+100 < LOUT) ? l0+100 : LOUT;
  for (int l4=l0; l4<lend; l4+=4){
    float a0[4]={0,0,0,0}, a1[4]={0,0,0,0};
    #pragma unroll
    for (int f=0;f<FIN;f++){
      float xw[24];
      #pragma unroll
      for (int j=0;j<6;j++){
        float4 v = *(const float4*)&xs[f][2*l4 + 4*j];
        xw[4*j+0]=v.x; xw[4*j+1]=v.y; xw[4*j+2]=v.z; xw[4*j+3]=v.w;
      }
      #pragma unroll
      for (int dl=0; dl<4; dl++){
        #pragma unroll
        for (int k=0;k<KW;k++){
          float wv = wr[f*KW+k];
          a0[dl] += wv*xw[2*dl+k];
          a1[dl] += wv*xw[2*dl+k+1];
        }
      }
    }
    #pragma unroll
    for (int dl=0; dl<4; dl++){
      int l = l4+dl;
      if (l < lend){
        float v = fmaxf(fmaxf(a0[dl],a1[dl])+cbv, 0.f);
        y16[((size_t)b*LOUT + l)*NF + c] = (_Float16)v;
        s += v; q += v*v;
      }
    }
  }
  rs[li][c]=s; rq[li][c]=q;
  __syncthreads();
  if (tid < 128){
    float ts = rs[0][c]+rs[1][c]+rs[2][c]+rs[3][c];
    float tq = rq[0][c]+rq[1][c]+rq[2][c]+rq[3][c];
    atomicAdd(&st[c], ts);
    atomicAdd(&st[128+c], tq);
  }
}

// -------- bias fold (gate-interleaved output order) --------
__global__ void k_prep_bias(const float* __restrict__ st,
    const float* __restrict__ g1, const float* __restrict__ b1v,
    const float* __restrict__ wf, const float* __restrict__ wb,
    const float* __restrict__ bif, const float* __restrict__ bhf,
    const float* __restrict__ bib, const float* __restrict__ bhb,
    float* __restrict__ bef, float* __restrict__ beb){
  int id = blockIdx.x*256 + threadIdx.x;
  if (id >= 2*NPAD) return;
  int dir = id/NPAD, g = id%NPAD;
  float* be = dir? beb : bef;
  if (g >= G4){ be[g]=0.f; return; }
  int src = (g&3)*HID + (g>>2);
  const float* wih = dir? wb : wf;
  float bias = dir? (bib[src]+bhb[src]) : (bif[src]+bhf[src]);
  const float Ninv = 1.f/((float)B_*(float)LOUT);
  for (int f=0;f<NF;f++){
    float m = st[f]*Ninv;
    float var = st[NF+f]*Ninv - m*m;
    float a = g1[f]*rsqrtf(var+EPS);
    float d = b1v[f] - m*a;
    bias += d*wih[(size_t)src*NF+f];
  }
  be[g] = bias;
}

// -------- pack AdaBN-folded w_ih into f16 MFMA fragments (interleaved cols) --------
__global__ void k_prep_wih(const float* __restrict__ st,
    const float* __restrict__ g1,
    const float* __restrict__ wf, const float* __restrict__ wb,
    _Float16* __restrict__ wT16){
  int id = blockIdx.x*256 + threadIdx.x;
  if (id >= 2*PNT*PKT*64) return;
  int lane = id & 63;
  int kt = (id>>6) & 3;
  int nt = (id>>8) % PNT;
  int dir = id / (PNT*PKT*64);
  const float* wih = dir? wb : wf;
  int n = nt*16 + (lane&15);
  int src = (n&3)*HID + (n>>2);
  int kb = kt*32 + (lane>>4)*8;
  const float Ninv = 1.f/((float)B_*(float)LOUT);
  half8 v;
  #pragma unroll
  for (int j=0;j<8;j++){
    int k = kb+j;
    float m = st[k]*Ninv;
    float var = st[NF+k]*Ninv - m*m;
    float a = g1[k]*rsqrtf(var+EPS);
    float f = (n < G4) ? wih[(size_t)src*NF + k]*a : 0.f;
    v[j] = (_Float16)f;
  }
  *(half8*)&wT16[(size_t)id*8] = v;
}

// -------- pack w_hh into f16 MFMA fragments (interleaved cols) --------
__global__ void k_prep_whh(const float* __restrict__ whf, const float* __restrict__ whb,
                           _Float16* __restrict__ wfrag){
  int id = blockIdx.x*256 + threadIdx.x;
  if (id >= 2*NT_*KT_*64) return;
  int lane = id & 63;
  int rest = id >> 6;
  int kt = rest % KT_;
  int nt = (rest/KT_) % NT_;
  int dir = rest / (KT_*NT_);
  const float* wh = dir? whb : whf;
  int n = nt*16 + (lane&15);
  int src = (n&3)*HID + (n>>2);
  int kb = kt*32 + (lane>>4)*8;
  half8 v;
  #pragma unroll
  for (int j=0;j<8;j++){
    int k = kb + j;
    float f = (n < G4 && k < HID) ? wh[(size_t)src*HID + k] : 0.f;
    v[j] = (_Float16)f;
  }
  *(half8*)&wfrag[(size_t)id*8] = v;
}

// ================= mega: rec M=8/8-wave (blocks < 128) + proj next chunk =================
__global__ __launch_bounds__(512)
void k_mega(const _Float16* __restrict__ wfrag,
            const _Float16* __restrict__ wT16,
            const float* __restrict__ bef, const float* __restrict__ beb,
            const _Float16* __restrict__ y16,
            const _Float16* __restrict__ prf, const _Float16* __restrict__ prb,
            _Float16* __restrict__ pwf, _Float16* __restrict__ pwb,
            float* __restrict__ hst, float* __restrict__ cst, float* __restrict__ mst,
            float* __restrict__ pooledT,
            int nrec, int tc, int first, int last, int t0p){
  __shared__ __align__(16) _Float16 hh[2][8][168];    // 5376 B
  __shared__ __align__(16) _Float16 pls[2][8][PSTR];  // 20736 B
  int tid = threadIdx.x;
  int bid = blockIdx.x;

  if (bid < nrec){
    // ---------------- rec path: 8 waves, 8 batches ----------------
    int dir = bid >> 6;
    int b0 = (bid & 63) * 8;
    const _Float16* pre = dir? prb : prf;
    int lane = tid & 63, w = tid >> 6;   // w 0..7

    int cnt  = (w<6) ? 5 : 4;
    int base = (w<6) ? 5*w : 30 + 4*(w-6);
    const _Float16* wf = wfrag + (size_t)dir*NT_*KT_*64*8;
    half8 bfr[5][5];
    #pragma unroll
    for (int i=0;i<5;i++){
      int ntc = (i<cnt)? (base+i) : base;
      #pragma unroll
      for (int kt=0;kt<KT_;kt++)
        bfr[i][kt] = *(const half8*)&wf[(size_t)((ntc*KT_+kt)*64 + lane)*8];
    }

    int batch = lane & 15;
    int brow = batch & 7;               // MFMA B reads dup rows for batch>=8 (cols unused)
    int uo[5]; bool uv[5];
    #pragma unroll
    for (int i=0;i<5;i++){
      uo[i] = (base+i)*4 + (lane>>4);
      uv[i] = (i<cnt) && (uo[i] < HID) && (batch < 8);
    }

    // staging: 640 half8 chunks = 8 rows x 80
    int srow0 = tid/80,        scol0 = (tid%80)*8;
    int srow1 = (tid+512)/80,  scol1 = ((tid+512)%80)*8;
    bool s2 = tid < 128;

    for (int i=tid; i<2*8*168; i+=512) (&hh[0][0][0])[i] = (_Float16)0.f;
    float c[5], m[5], hl[5];
    #pragma unroll
    for (int i=0;i<5;i++){ c[i]=0.f; m[i]=-1e30f; hl[i]=0.f; }
    __syncthreads();
    if (!first){
      #pragma unroll
      for (int i=0;i<5;i++){
        if (uv[i]){
          size_t gi = ((size_t)(dir*B_ + b0 + batch))*HSTR + uo[i];
          c[i]=cst[gi]; m[i]=mst[gi]; hl[i]=hst[gi];
          hh[0][batch][uo[i]] = (_Float16)hl[i];
        }
      }
    }
    {
      half8 s0 = *(const half8*)(pre + ((size_t)(b0 + srow0))*NPAD + scol0);
      *(half8*)&pls[0][srow0][scol0] = s0;
      if (s2){
        half8 s1 = *(const half8*)(pre + ((size_t)(b0 + srow1))*NPAD + scol1);
        *(half8*)&pls[0][srow1][scol1] = s1;
      }
    }
    __syncthreads();

    int cur = 0;
    for (int t=0; t<tc; t++){
      int nxt = cur ^ 1;
      half8 s0, s1;
      bool ld = (t+1 < tc);
      if (ld){
        size_t rbase = (size_t)(t+1)*B_ + b0;
        s0 = *(const half8*)(pre + (rbase + srow0)*NPAD + scol0);
        if (s2) s1 = *(const half8*)(pre + (rbase + srow1)*NPAD + scol1);
      }
      f32x4 acc0={0,0,0,0}, acc1={0,0,0,0}, acc2={0,0,0,0}, acc3={0,0,0,0}, acc4={0,0,0,0};
      #pragma unroll
      for (int kt=0; kt<KT_; kt++){
        half8 a = *(const half8*)&hh[cur][brow][kt*32 + (lane>>4)*8];
        acc0 = __builtin_amdgcn_mfma_f32_16x16x32_f16(bfr[0][kt], a, acc0, 0,0,0);
        acc1 = __builtin_amdgcn_mfma_f32_16x16x32_f16(bfr[1][kt], a, acc1, 0,0,0);
        acc2 = __builtin_amdgcn_mfma_f32_16x16x32_f16(bfr[2][kt], a, acc2, 0,0,0);
        acc3 = __builtin_amdgcn_mfma_f32_16x16x32_f16(bfr[3][kt], a, acc3, 0,0,0);
        if (cnt>4) acc4 = __builtin_amdgcn_mfma_f32_16x16x32_f16(bfr[4][kt], a, acc4, 0,0,0);
      }
      #define CELL(ACC, I)                                                     \
      if (uv[I]){                                                              \
        half4 pv = *(const half4*)&pls[cur][batch][4*uo[I]];                   \
        float xi = ACC[0] + (float)pv[0];                                      \
        float xf = ACC[1] + (float)pv[1];                                      \
        float xg = ACC[2] + (float)pv[2];                                      \
        float xo = ACC[3] + (float)pv[3];                                      \
        float ig=hsig(xi), fg=hsig(xf), og=hsig(xo), gg=ftanh(xg);             \
        c[I] = fg*c[I] + ig*gg;                                                \
        float hv = og*ftanh(c[I]);                                             \
        m[I] = fmaxf(m[I], hv);                                                \
        hl[I] = hv;                                                            \
        hh[nxt][batch][uo[I]] = (_Float16)hv;                                  \
      }
      CELL(acc0, 0)
      CELL(acc1, 1)
      CELL(acc2, 2)
      CELL(acc3, 3)
      CELL(acc4, 4)
      #undef CELL
      if (ld){
        *(half8*)&pls[nxt][srow0][scol0] = s0;
        if (s2) *(half8*)&pls[nxt][srow1][scol1] = s1;
      }
      __syncthreads();
      cur = nxt;
    }

    #pragma unroll
    for (int i=0;i<5;i++){
      if (uv[i]){
        size_t gi = ((size_t)(dir*B_ + b0 + batch))*HSTR + uo[i];
        cst[gi]=c[i]; mst[gi]=m[i]; hst[gi]=hl[i];
        if (last) pooledT[(size_t)(dir*HID + uo[i])*512 + b0 + batch] = m[i];
      }
    }
    return;
  }

  // ---------------- proj path: 8 waves x 16 rows = 128 rows x 128 cols ----------------
  {
    int pb = bid - nrec;
    int dir  = pb & 1;
    int t5   = pb >> 1;
    int by   = t5 % 5;
    int t4   = t5 / 5;
    int mb   = t4 & 3;
    int trel = t4 >> 2;
    const _Float16* wfp = wT16 + (size_t)dir*PNT*PKT*64*8;
    const float* be = dir? beb : bef;
    _Float16* pre = dir? pwb : pwf;
    int t = dir ? (LOUT-1-t0p-trel) : (t0p+trel);
    int n0 = by*128, nb = n0>>4;
    int lane = tid & 63, ww = tid >> 6;
    int m0 = mb*128 + ww*16;
    int arow = lane&15, aq = (lane>>4)*8;
    const _Float16* ap = y16 + ((size_t)(m0+arow)*LOUT + t)*NF + aq;
    f32x4 acc[8];
    #pragma unroll
    for (int j=0;j<8;j++) acc[j] = (f32x4){0,0,0,0};
    #pragma unroll
    for (int kt=0; kt<PKT; kt++){
      half8 a = *(const half8*)(ap + kt*32);
      #pragma unroll
      for (int nt=0; nt<8; nt++){
        half8 bf = *(const half8*)&wfp[(size_t)(((nb+nt)*PKT + kt)*64 + lane)*8];
        acc[nt] = __builtin_amdgcn_mfma_f32_16x16x32_f16(a, bf, acc[nt], 0,0,0);
      }
    }
    int dcol = lane&15, dq = (lane>>4)*4;
    size_t rowg = (size_t)trel*B_ + m0 + dq;
    #pragma unroll
    for (int nt=0; nt<8; nt++){
      int colL = n0 + nt*16 + dcol;
      float bv = be[colL];
      #pragma unroll
      for (int r=0;r<4;r++)
        pre[(rowg+r)*NPAD + colL] = (_Float16)(acc[nt][r] + bv);
    }
  }
}

// ---------------- tails ----------------
__global__ __launch_bounds__(256) void k_stats2(const float* __restrict__ pooledT,
    const float* __restrict__ g2, const float* __restrict__ b2,
    float* __restrict__ a2, float* __restrict__ d2){
  int f = blockIdx.x;           // 300
  int t = threadIdx.x;          // 256
  float v1 = pooledT[(size_t)f*512 + t];
  float v2 = pooledT[(size_t)f*512 + 256 + t];
  float s = v1+v2, q = v1*v1+v2*v2;
  #pragma unroll
  for (int off=1; off<64; off<<=1){ s += __shfl_xor(s,off); q += __shfl_xor(q,off); }
  __shared__ float ls[4], lq[4];
  int lane = t & 63, w = t >> 6;
  if (lane==0){ ls[w]=s; lq[w]=q; }
  __syncthreads();
  if (t==0){
    s = ls[0]+ls[1]+ls[2]+ls[3];
    q = lq[0]+lq[1]+lq[2]+lq[3];
    float m = s*(1.f/B_), var = q*(1.f/B_) - m*m;
    float a = g2[f]*rsqrtf(var+EPS);
    a2[f]=a; d2[f]=b2[f]-m*a;
  }
}

__global__ void k_fc1(const float* __restrict__ pooledT,
    const float* __restrict__ a2, const float* __restrict__ d2,
    const float* __restrict__ w1, const float* __restrict__ fb1,
    float* __restrict__ z1){
  int o = blockIdx.x*256 + threadIdx.x;
  if (o >= B_*50) return;
  int b = o/50, j = o%50;
  float acc = fb1[j];
  for (int f=0;f<300;f++)
    acc += (a2[f]*pooledT[(size_t)f*512 + b] + d2[f]) * w1[j*300+f];
  z1[o] = fmaxf(acc,0.f);
}

__global__ __launch_bounds__(64) void k_stats3(const float* __restrict__ z1,
    const float* __restrict__ g3, const float* __restrict__ b3,
    float* __restrict__ a3, float* __restrict__ d3){
  int f = blockIdx.x;           // 50
  int t = threadIdx.x;          // 64
  float s=0.f,q=0.f;
  #pragma unroll
  for (int k=0;k<8;k++){ float v = z1[(size_t)(t + 64*k)*50 + f]; s+=v; q+=v*v; }
  #pragma unroll
  for (int off=1; off<64; off<<=1){ s += __shfl_xor(s,off); q += __shfl_xor(q,off); }
  if (t==0){
    float m = s*(1.f/B_), var = q*(1.f/B_) - m*m;
    float a = g3[f]*rsqrtf(var+EPS);
    a3[f]=a; d3[f]=b3[f]-m*a;
  }
}

__global__ void k_fc2(const float* __restrict__ z1,
    const float* __restrict__ a3, const float* __restrict__ d3,
    const float* __restrict__ w2, const float* __restrict__ fb2,
    float* __restrict__ out){
  int b = blockIdx.x;
  int t = threadIdx.x;
  __shared__ float zl[50];
  __shared__ float lg[10];
  if (t<50) zl[t] = a3[t]*z1[(size_t)b*50+t] + d3[t];
  __syncthreads();
  if (t<10){
    float acc = fb2[t];
    for (int j=0;j<50;j++) acc += zl[j]*w2[t*50+j];
    lg[t]=acc;
  }
  __syncthreads();
  if (t<10){
    float m = lg[0];
    #pragma unroll
    for (int i=1;i<10;i++) m = fmaxf(m,lg[i]);
    float s = 0.f;
    #pragma unroll
    for (int i=0;i<10;i++) s += expf(lg[i]-m);
    out[(size_t)b*10+t] = expf(lg[t]-m)/s;
  }
}

extern "C" void kernel_launch(void* const* d_in, const int* in_sizes, int n_in,
                              void* d_out, int out_size, void* d_ws, size_t ws_size,
                              hipStream_t stream) {
  const float* x    = (const float*)d_in[0];
  const float* cw   = (const float*)d_in[1];
  const float* cb   = (const float*)d_in[2];
  const float* g1   = (const float*)d_in[3];
  const float* b1v  = (const float*)d_in[4];
  const float* wihf = (const float*)d_in[5];
  const float* whhf = (const float*)d_in[6];
  const float* bihf = (const float*)d_in[7];
  const float* bhhf = (const float*)d_in[8];
  const float* wihb = (const float*)d_in[9];
  const float* whhb = (const float*)d_in[10];
  const float* bihb = (const float*)d_in[11];
  const float* bhhb = (const float*)d_in[12];
  const float* g2   = (const float*)d_in[13];
  const float* b2   = (const float*)d_in[14];
  const float* w1   = (const float*)d_in[15];
  const float* fb1  = (const float*)d_in[16];
  const float* g3   = (const float*)d_in[17];
  const float* b3   = (const float*)d_in[18];
  const float* w2   = (const float*)d_in[19];
  const float* fb2  = (const float*)d_in[20];
  float* out = (float*)d_out;

  uint8_t* base = (uint8_t*)d_ws;
  size_t off = 0;
  auto allocB = [&](size_t nbytes)->uint8_t*{
    uint8_t* p = base + off;
    off = (off + nbytes + 255) & ~(size_t)255;
    return p;
  };
  _Float16* y16    = (_Float16*)allocB((size_t)B_*LOUT*NF*2);
  float* st        = (float*)allocB(256*4);
  _Float16* wT16   = (_Float16*)allocB((size_t)2*PNT*PKT*64*8*2);
  float* bef       = (float*)allocB(NPAD*4);
  float* beb       = (float*)allocB(NPAD*4);
  _Float16* wfrag  = (_Float16*)allocB((size_t)2*NT_*KT_*64*8*2);
  float* hst       = (float*)allocB((size_t)2*B_*HSTR*4);
  float* cst       = (float*)allocB((size_t)2*B_*HSTR*4);
  float* mst       = (float*)allocB((size_t)2*B_*HSTR*4);
  float* pooledT   = (float*)allocB((size_t)300*512*4);
  float* a2        = (float*)allocB(320*4);
  float* d2        = (float*)allocB(320*4);
  float* z1        = (float*)allocB((size_t)B_*50*4);
  float* a3        = (float*)allocB(64*4);
  float* d3        = (float*)allocB(64*4);
  size_t fixedEnd = off;

  size_t avail = (ws_size > fixedEnd + 4096) ? (ws_size - fixedEnd - 4096) : 0;
  size_t per_t1 = (size_t)2*B_*NPAD*2;
  size_t per_t2 = (size_t)4*B_*NPAD*2;
  int nch, TC;
  if (avail / per_t1 >= (size_t)LOUT){
    nch = 1; TC = LOUT;
  } else {
    int tcmax = (int)(avail / per_t2);
    if (tcmax < 1) tcmax = 1;
    if (tcmax > LOUT) tcmax = LOUT;
    nch = (LOUT + tcmax - 1) / tcmax;
    TC = (LOUT + nch - 1) / nch;
  }
  _Float16* preA_f = (_Float16*)allocB((size_t)TC*B_*NPAD*2);
  _Float16* preA_b = (_Float16*)allocB((size_t)TC*B_*NPAD*2);
  _Float16* preB_f = preA_f;
  _Float16* preB_b = preA_b;
  if (nch > 1){
    preB_f = (_Float16*)allocB((size_t)TC*B_*NPAD*2);
    preB_b = (_Float16*)allocB((size_t)TC*B_*NPAD*2);
  }
  auto t0of = [&](int k){ return k*TC; };
  auto tcof = [&](int k){ int r = LOUT - k*TC; return (r < TC) ? r : TC; };

  hipMemsetAsync(st, 0, 256*4, stream);
  k_conv3<<<B_, 512, 0, stream>>>(x, cw, cb, y16, st);
  k_prep_bias<<<(2*NPAD+255)/256, 256, 0, stream>>>(st, g1, b1v, wihf, wihb,
                                                    bihf, bhhf, bihb, bhhb, bef, beb);
  k_prep_wih<<<(2*PNT*PKT*64+255)/256, 256, 0, stream>>>(st, g1, wihf, wihb, wT16);
  k_prep_whh<<<(2*NT_*KT_*64+255)/256, 256, 0, stream>>>(whhf, whhb, wfrag);

  // launch 0: proj-only for chunk 0 -> set A
  k_mega<<<tcof(0)*40, 512, 0, stream>>>(wfrag, wT16, bef, beb, y16,
      preA_f, preA_b, preA_f, preA_b, hst, cst, mst, pooledT,
      0, 0, 0, 0, t0of(0));
  // chunk loop: rec(k) on set(k%2) || proj(k+1) -> set((k+1)%2)
  for (int k=0; k<nch; k++){
    int hasN = (k+1 < nch) ? 1 : 0;
    _Float16* rf = (k & 1) ? preB_f : preA_f;
    _Float16* rb = (k & 1) ? preB_b : preA_b;
    _Float16* wf_ = ((k+1) & 1) ? preB_f : preA_f;
    _Float16* wb_ = ((k+1) & 1) ? preB_b : preA_b;
    int grid = 128 + (hasN ? tcof(k+1)*40 : 0);
    k_mega<<<grid, 512, 0, stream>>>(wfrag, wT16, bef, beb, y16,
        rf, rb, wf_, wb_, hst, cst, mst, pooledT,
        128, tcof(k), (k==0) ? 1 : 0, hasN ? 0 : 1, hasN ? t0of(k+1) : 0);
  }

  k_stats2<<<300, 256, 0, stream>>>(pooledT, g2, b2, a2, d2);
  k_fc1<<<(B_*50+255)/256, 256, 0, stream>>>(pooledT, a2, d2, w1, fb1, z1);
  k_stats3<<<50, 64, 0, stream>>>(z1, g3, b3, a3, d3);
  k_fc2<<<B_, 64, 0, stream>>>(z1, a3, d3, w2, fb2, out);
}